// Round 4
// baseline (6691.048 us; speedup 1.0000x reference)
//
#include <hip/hip_runtime.h>
#include <hip/hip_fp16.h>
#include <math.h>

// DirModelToFace on MI355X — round 4:
//  * fp16 shadow copies of v/f in batch-interleaved [r4][b][32] layout: spmm gather
//    is one contiguous 256B blob per edge (2 full 128B lines) -> gather traffic halves.
//    Shadows written in GEMM/conv1 epilogues. (fp16 in old [b][r4][32] layout would
//    fetch half-used lines -> no win; the interleave is the point.)
//  * per-layer S/avgacc memsets -> pre-zeroed arenas (1 memset at launch start);
//    CSR ptr->fill memcpy folded into apply_kernel. ~50 fewer dispatches.
// Round-3 profile: spmm 125us x16 (FETCH 254MB vs 25-49MB unique; gather-BW-bound).

#define EPS 1e-5f

typedef float floatx4 __attribute__((ext_vector_type(4)));
typedef short shortx8 __attribute__((ext_vector_type(8)));

__device__ __forceinline__ float eluf(float x) { return x > 0.f ? x : expm1f(x); }
__device__ __forceinline__ float4 elu4(float4 v) {
    v.x = eluf(v.x); v.y = eluf(v.y); v.z = eluf(v.z); v.w = eluf(v.w); return v;
}
__device__ __forceinline__ short f2bf(float x) {  // round-to-nearest-even bf16
    unsigned u = __builtin_bit_cast(unsigned, x);
    u = u + 0x7FFFu + ((u >> 16) & 1u);
    return (short)(u >> 16);
}
__device__ __forceinline__ float bf2f(short h) {
    unsigned u = ((unsigned)(unsigned short)h) << 16;
    return __builtin_bit_cast(float, u);
}

// v = inputs @ W1 + b1; also writes fp16 shadow vH[(4*vert+(c>>5))*128 + b*32 + (c&31)]
__global__ void conv1_kernel(const float* __restrict__ in, const float* __restrict__ W1,
                             const float* __restrict__ b1, float* __restrict__ v,
                             __half* __restrict__ vH, int N) {
    int idx = blockIdx.x * 256 + threadIdx.x;
    int r = idx >> 7, c = idx & 127;
    float x0 = in[r * 3 + 0], x1 = in[r * 3 + 1], x2 = in[r * 3 + 2];
    float val = b1[c] + x0 * W1[c] + x1 * W1[128 + c] + x2 * W1[256 + c];
    v[(size_t)r * 128 + c] = val;
    int b = r / N, vert = r - b * N;
    vH[(size_t)(4 * vert + (c >> 5)) * 128 + b * 32 + (c & 31)] = __float2half(val);
}

// ---------------- CSR build ----------------

__global__ void hist_kernel(const int* __restrict__ rows, int* __restrict__ counts) {
    int e = blockIdx.x * 256 + threadIdx.x;
    atomicAdd(&counts[rows[e]], 1);
}

__global__ void partial_kernel(const int* __restrict__ counts, int* __restrict__ partials,
                               int R) {
    int t = threadIdx.x;
    int base = blockIdx.x * 1024 + t * 4;
    int s = 0;
#pragma unroll
    for (int j = 0; j < 4; ++j) { int i = base + j; if (i < R) s += counts[i]; }
    __shared__ int sh[256];
    sh[t] = s; __syncthreads();
    for (int st = 128; st > 0; st >>= 1) {
        if (t < st) sh[t] += sh[t + st];
        __syncthreads();
    }
    if (t == 0) partials[blockIdx.x] = sh[0];
}

__global__ void scanp_kernel(int* __restrict__ partials, int* __restrict__ rowptr,
                             int P, int R, int total) {
    __shared__ int sh[256];
    int t = threadIdx.x;
    int v = (t < P) ? partials[t] : 0;
    sh[t] = v; __syncthreads();
    for (int st = 1; st < 256; st <<= 1) {
        int tmp = (t >= st) ? sh[t - st] : 0;
        __syncthreads();
        sh[t] += tmp;
        __syncthreads();
    }
    if (t < P) partials[t] = sh[t] - v;
    if (t == 0) rowptr[R] = total;
}

// per-chunk exclusive scan + offset -> rowptr; also re-writes counts[] as fill cursor
__global__ void apply_kernel(int* __restrict__ counts, const int* __restrict__ partials,
                             int* __restrict__ rowptr, int R) {
    int t = threadIdx.x;
    int base = blockIdx.x * 1024 + t * 4;
    int c[4]; int s = 0;
#pragma unroll
    for (int j = 0; j < 4; ++j) { int i = base + j; c[j] = (i < R) ? counts[i] : 0; s += c[j]; }
    __shared__ int sh[256];
    sh[t] = s; __syncthreads();
    for (int st = 1; st < 256; st <<= 1) {
        int tmp = (t >= st) ? sh[t - st] : 0;
        __syncthreads();
        sh[t] += tmp;
        __syncthreads();
    }
    int off = partials[blockIdx.x] + sh[t] - s;
#pragma unroll
    for (int j = 0; j < 4; ++j) {
        int i = base + j;
        if (i < R) { rowptr[i] = off; counts[i] = off; }
        off += c[j];
    }
}

__global__ void scatter_kernel(const int* __restrict__ rows, const int* __restrict__ cols,
                               const float* __restrict__ vals, int* __restrict__ fill,
                               int* __restrict__ cols_s, float* __restrict__ vals_s) {
    int e = blockIdx.x * 256 + threadIdx.x;
    int p = atomicAdd(&fill[rows[e]], 1);
    cols_s[p] = cols[e];
    vals_s[p] = vals[e];
}

// ---------------- CSR spmm: gather from fp16 shadow [co][b][32] ----------------
__global__ __launch_bounds__(256) void spmm_csr_kernel(
    const int* __restrict__ rowptr, const int* __restrict__ cols,
    const float* __restrict__ vals, const __half* __restrict__ xH,
    float* __restrict__ y, int R4) {
    int r = blockIdx.x * 4 + (threadIdx.x >> 6);
    int lane = threadIdx.x & 63;
    int b = lane >> 5;
    int c = lane & 31;
    const __half* x0 = xH + b * 32 + c;        // batches b and b+2
    const __half* x1 = xH + (b + 2) * 32 + c;
    int e0 = rowptr[r], e1 = rowptr[r + 1];
    float a0 = 0.f, a1 = 0.f;
    for (int e = e0; e < e1; ++e) {
        int co = cols[e];
        float va = vals[e];
        size_t o = (size_t)co * 128;
        a0 += va * __half2float(x0[o]);
        a1 += va * __half2float(x1[o]);
    }
    size_t rs = (size_t)R4 * 32;
    size_t ro = (size_t)r * 32 + c;
    y[(size_t)b * rs + ro] = a0;
    y[(size_t)(b + 2) * rs + ro] = a1;
}

// per-channel sums/sumsq over rows of X = [elu(A) | B-half]
__global__ void stats_kernel(const float* __restrict__ A, const float* __restrict__ Bs,
                             float* __restrict__ S, int R, int rpb, int rowsPerBatch,
                             int modeB, int eluB) {
    int t = threadIdx.x;
    int r0 = blockIdx.x * rpb;
    int r1 = min(r0 + rpb, R);
    float s1 = 0.f, s2 = 0.f;
    if (t < 128) {
        for (int r = r0; r < r1; ++r) {
            float v = eluf(A[(size_t)r * 128 + t]);
            s1 += v; s2 += v * v;
        }
    } else {
        int c = t - 128;
        if (modeB == 0) {
            for (int r = r0; r < r1; ++r) {
                float v = Bs[(size_t)r * 128 + c];
                if (eluB) v = eluf(v);
                s1 += v; s2 += v * v;
            }
        } else {
            for (int r = r0; r < r1; ++r) {
                float v = Bs[(r / rowsPerBatch) * 128 + c];
                s1 += v; s2 += v * v;
            }
        }
    }
    atomicAdd(&S[t], s1);
    atomicAdd(&S[256 + t], s2);
}

// Fold BN into weights; emit bf16 hi/lo split in [col][k] layout for MFMA B-frags.
__global__ void fold_kernel(const float* __restrict__ S, const float* __restrict__ gamma,
                            const float* __restrict__ beta, const float* __restrict__ W,
                            const float* __restrict__ bvec, short* __restrict__ Wh,
                            short* __restrict__ Wl, float* __restrict__ bp, float invR) {
    __shared__ float red[256];
    int o = blockIdx.x, k = threadIdx.x;
    float mean = S[k] * invR;
    float var = S[256 + k] * invR - mean * mean;
    float s = gamma[k] / sqrtf(var + EPS);
    float w = W[(size_t)k * 128 + o];
    float wp = s * w;
    short h = f2bf(wp);
    Wh[(size_t)o * 256 + k] = h;
    Wl[(size_t)o * 256 + k] = f2bf(wp - bf2f(h));
    red[k] = (beta[k] - mean * s) * w;
    __syncthreads();
    for (int st = 128; st > 0; st >>= 1) {
        if (k < st) red[k] += red[k + st];
        __syncthreads();
    }
    if (k == 0) bp[o] = bvec[o] + red[0];
}

// MFMA GEMM (bf16 hi/lo split, fp32 acc). Optional fp16 shadow write in epilogue.
__global__ __launch_bounds__(256) void gemm_mfma(
    const float* __restrict__ A, const float* __restrict__ Bs,
    const short* __restrict__ Wh, const short* __restrict__ Wl,
    const float* __restrict__ bp, const float* __restrict__ resid,
    float* __restrict__ out, __half* __restrict__ shadow,
    int rowsPerBatch, int modeB, int eluB) {
    const int lane = threadIdx.x & 63;
    const int wave = threadIdx.x >> 6;
    const int rowBase = blockIdx.x * 128 + wave * 32;
    const int m = lane & 15;
    const int kq = lane >> 4;
    floatx4 acc[2][8];
#pragma unroll
    for (int i = 0; i < 2; ++i)
#pragma unroll
        for (int j = 0; j < 8; ++j) acc[i][j] = {0.f, 0.f, 0.f, 0.f};

    for (int kb = 0; kb < 8; ++kb) {
        const int k0 = kb * 32 + kq * 8;
        shortx8 ah[2], al[2];
#pragma unroll
        for (int rg = 0; rg < 2; ++rg) {
            int row = rowBase + rg * 16 + m;
            float4 p, q;
            if (kb < 4) {
                p = elu4(*(const float4*)&A[(size_t)row * 128 + k0]);
                q = elu4(*(const float4*)&A[(size_t)row * 128 + k0 + 4]);
            } else {
                int kk = k0 - 128;
                if (modeB == 0) {
                    p = *(const float4*)&Bs[(size_t)row * 128 + kk];
                    q = *(const float4*)&Bs[(size_t)row * 128 + kk + 4];
                    if (eluB) { p = elu4(p); q = elu4(q); }
                } else {
                    int b = row / rowsPerBatch;
                    p = *(const float4*)&Bs[b * 128 + kk];
                    q = *(const float4*)&Bs[b * 128 + kk + 4];
                }
            }
            float x[8] = {p.x, p.y, p.z, p.w, q.x, q.y, q.z, q.w};
#pragma unroll
            for (int j = 0; j < 8; ++j) {
                short h = f2bf(x[j]);
                ah[rg][j] = h;
                al[rg][j] = f2bf(x[j] - bf2f(h));
            }
        }
#pragma unroll
        for (int ct = 0; ct < 8; ++ct) {
            shortx8 bh = *(const shortx8*)&Wh[(size_t)(ct * 16 + m) * 256 + k0];
            shortx8 bl = *(const shortx8*)&Wl[(size_t)(ct * 16 + m) * 256 + k0];
#pragma unroll
            for (int rg = 0; rg < 2; ++rg) {
                acc[rg][ct] = __builtin_amdgcn_mfma_f32_16x16x32_bf16(ah[rg], bh, acc[rg][ct], 0, 0, 0);
                acc[rg][ct] = __builtin_amdgcn_mfma_f32_16x16x32_bf16(ah[rg], bl, acc[rg][ct], 0, 0, 0);
                acc[rg][ct] = __builtin_amdgcn_mfma_f32_16x16x32_bf16(al[rg], bh, acc[rg][ct], 0, 0, 0);
            }
        }
    }
    // C/D layout col=lane&15, row=(lane>>4)*4+reg  [verified m89/m91]
#pragma unroll
    for (int ct = 0; ct < 8; ++ct) {
        int col = ct * 16 + m;
        float bb = bp[col];
#pragma unroll
        for (int rg = 0; rg < 2; ++rg) {
#pragma unroll
            for (int r = 0; r < 4; ++r) {
                int row = rowBase + rg * 16 + kq * 4 + r;
                size_t o = (size_t)row * 128 + col;
                float v = acc[rg][ct][r] + bb;
                if (resid) v += resid[o];
                out[o] = v;
                if (shadow) {
                    int b = row / rowsPerBatch, vert = row - b * rowsPerBatch;
                    shadow[(size_t)(4 * vert + (col >> 5)) * 128 + b * 32 + (col & 31)] =
                        __float2half(v);
                }
            }
        }
    }
}

// masked mean of elu(X): partial sums via atomics into pre-zeroed arena slot
__global__ void avgpool_kernel(const float* __restrict__ X, const float* __restrict__ mask,
                               float* __restrict__ avgacc, float* __restrict__ masksum,
                               int N, int rpb) {
    int b = blockIdx.y, t = threadIdx.x;
    int n0 = blockIdx.x * rpb;
    int n1 = min(n0 + rpb, N);
    float acc = 0.f, mac = 0.f;
    for (int n = n0; n < n1; ++n) {
        float m = mask[(size_t)b * N + n];
        float v = eluf(X[((size_t)b * N + n) * 128 + t]);
        acc += m * v;
        mac += m;
    }
    atomicAdd(&avgacc[b * 128 + t], acc);
    if (t == 0) atomicAdd(&masksum[b], mac);
}

__global__ void finalize_avg(const float* __restrict__ avgacc, const float* __restrict__ masksum,
                             float* __restrict__ avg, float* __restrict__ S, float fN) {
    int c = threadIdx.x;
    float s1 = 0.f, s2 = 0.f;
    for (int b = 0; b < 4; ++b) {
        float a = avgacc[b * 128 + c] / masksum[b];
        avg[b * 128 + c] = a;
        s1 += a; s2 += a * a;
    }
    S[128 + c] = s1 * fN;
    S[256 + 128 + c] = s2 * fN;
}

__global__ void fold_final(const float* __restrict__ S, const float* __restrict__ g2,
                           const float* __restrict__ be2, const float* __restrict__ W2,
                           const float* __restrict__ b2, float* __restrict__ W2p, float invR) {
    __shared__ float red[128];
    int c = threadIdx.x;
    float mean = S[c] * invR;
    float var = S[256 + c] * invR - mean * mean;
    float s = g2[c] / sqrtf(var + EPS);
    float w = W2[c];
    W2p[c] = s * w;
    red[c] = (be2[c] - mean * s) * w;
    __syncthreads();
    for (int st = 64; st > 0; st >>= 1) {
        if (c < st) red[c] += red[c + st];
        __syncthreads();
    }
    if (c == 0) W2p[128] = b2[0] + red[0];
}

__global__ void final_out_kernel(const float* __restrict__ f, const float* __restrict__ W2p,
                                 float* __restrict__ out) {
    int t = threadIdx.x;
    int w = t >> 6, lane = t & 63;
    int row = blockIdx.x * 4 + w;
    float a = eluf(f[(size_t)row * 128 + lane]) * W2p[lane] +
              eluf(f[(size_t)row * 128 + 64 + lane]) * W2p[64 + lane];
    for (int off = 32; off > 0; off >>= 1) a += __shfl_down(a, off);
    if (lane == 0) out[row] = a + W2p[128];
}

extern "C" void kernel_launch(void* const* d_in, const int* in_sizes, int n_in,
                              void* d_out, int out_size, void* d_ws, size_t ws_size,
                              hipStream_t stream) {
    const float* inputs = (const float*)d_in[0];
    const float* mask = (const float*)d_in[1];
    const int* Di_rows = (const int*)d_in[2];
    const int* Di_cols = (const int*)d_in[3];
    const float* Di_vals = (const float*)d_in[4];
    const int* DiA_rows = (const int*)d_in[5];
    const int* DiA_cols = (const int*)d_in[6];
    const float* DiA_vals = (const float*)d_in[7];
    const float* W1 = (const float*)d_in[8];
    const float* b1 = (const float*)d_in[9];
    const float* rn_gamma = (const float*)d_in[10];
    const float* rn_beta = (const float*)d_in[11];
    const float* rn_W = (const float*)d_in[12];
    const float* rn_b = (const float*)d_in[13];
    const float* g2 = (const float*)d_in[14];
    const float* be2 = (const float*)d_in[15];
    const float* W2 = (const float*)d_in[16];
    const float* b2 = (const float*)d_in[17];
    float* out = (float*)d_out;

    const int B = 4;
    const int BN = in_sizes[1];      // 48000
    const int N = BN / B;            // 12000
    const int BF = out_size;         // 96000
    const int Fn = BF / B;           // 24000
    const int nnz = in_sizes[2];     // 1,152,000
    const int RA = 4 * N;            // 48000
    const int RD = 4 * Fn;           // 96000

    float* ws = (float*)d_ws;
    size_t off = 0;
    float* vA = ws + off;  off += (size_t)BN * 128;
    float* fA = ws + off;  off += (size_t)BF * 128;
    float* msg = ws + off; off += (size_t)BF * 128;
    __half* vH = (__half*)(ws + off); off += (size_t)RA * 128 / 2;  // [co][b][32] fp16
    __half* fH = (__half*)(ws + off); off += (size_t)RD * 128 / 2;
    int* ptrA   = (int*)(ws + off);   off += (size_t)RA + 4;
    int* colsA  = (int*)(ws + off);   off += (size_t)nnz;
    float* valsA = ws + off;          off += (size_t)nnz;
    int* ptrD   = (int*)(ws + off);   off += (size_t)RD + 4;
    int* colsD  = (int*)(ws + off);   off += (size_t)nnz;
    float* valsD = ws + off;          off += (size_t)nnz;
    int* tmpfill = (int*)(ws + off);  off += (size_t)RD;
    int* partials = (int*)(ws + off); off += 256;
    // pre-zeroed arenas: 33 stats slots (512 ea) + 16 avg slots (516 ea)
    float* Sarena = ws + off; off += 33 * 512;
    float* Aarena = ws + off; off += 16 * 516;
    float* avg = ws + off;    off += 512;
    short* Wh = (short*)(ws + off); off += 128 * 256 / 2;
    short* Wl = (short*)(ws + off); off += 128 * 256 / 2;
    float* bp = ws + off;  off += 128;
    float* W2p = ws + off; off += 132;

    const int eBlocks = nnz / 256;
    const int PA = (RA + 1023) / 1024;
    const int PD = (RD + 1023) / 1024;

    // one-shot zeroing: arenas + fA + fH
    hipMemsetAsync(Sarena, 0, (33 * 512 + 16 * 516) * 4, stream);
    hipMemsetAsync(fA, 0, (size_t)BF * 128 * 4, stream);
    hipMemsetAsync(fH, 0, (size_t)RD * 128 * 2, stream);

    // ---- build CSR for DiA ----
    hipMemsetAsync(tmpfill, 0, (size_t)RA * 4, stream);
    hist_kernel<<<eBlocks, 256, 0, stream>>>(DiA_rows, tmpfill);
    partial_kernel<<<PA, 256, 0, stream>>>(tmpfill, partials, RA);
    scanp_kernel<<<1, 256, 0, stream>>>(partials, ptrA, PA, RA, nnz);
    apply_kernel<<<PA, 256, 0, stream>>>(tmpfill, partials, ptrA, RA);
    scatter_kernel<<<eBlocks, 256, 0, stream>>>(DiA_rows, DiA_cols, DiA_vals, tmpfill,
                                                colsA, valsA);
    // ---- build CSR for Di ----
    hipMemsetAsync(tmpfill, 0, (size_t)RD * 4, stream);
    hist_kernel<<<eBlocks, 256, 0, stream>>>(Di_rows, tmpfill);
    partial_kernel<<<PD, 256, 0, stream>>>(tmpfill, partials, RD);
    scanp_kernel<<<1, 256, 0, stream>>>(partials, ptrD, PD, RD, nnz);
    apply_kernel<<<PD, 256, 0, stream>>>(tmpfill, partials, ptrD, RD);
    scatter_kernel<<<eBlocks, 256, 0, stream>>>(Di_rows, Di_cols, Di_vals, tmpfill,
                                                colsD, valsD);

    conv1_kernel<<<BN * 128 / 256, 256, 0, stream>>>(inputs, W1, b1, vA, vH, N);

    int sslot = 0, aslot = 0;
    for (int i = 0; i < 16; ++i) {
        if ((i & 1) == 0) {
            const float* g0 = rn_gamma + (size_t)(i * 2 + 0) * 256;
            const float* be0 = rn_beta + (size_t)(i * 2 + 0) * 256;
            const float* Wl0 = rn_W + (size_t)(i * 2 + 0) * 256 * 128;
            const float* bl0 = rn_b + (size_t)(i * 2 + 0) * 128;
            const float* g1 = rn_gamma + (size_t)(i * 2 + 1) * 256;
            const float* be1 = rn_beta + (size_t)(i * 2 + 1) * 256;
            const float* Wl1 = rn_W + (size_t)(i * 2 + 1) * 256 * 128;
            const float* bl1 = rn_b + (size_t)(i * 2 + 1) * 128;

            // msg_v = DiA @ f (gather fH)
            float* S = Sarena + 512 * sslot++;
            spmm_csr_kernel<<<RA / 4, 256, 0, stream>>>(ptrA, colsA, valsA, fH, msg, RA);
            stats_kernel<<<BN / 64, 256, 0, stream>>>(vA, msg, S, BN, 64, N, 0, 1);
            fold_kernel<<<128, 256, 0, stream>>>(S, g0, be0, Wl0, bl0, Wh, Wl, bp, 1.f / BN);
            gemm_mfma<<<BN / 128, 256, 0, stream>>>(vA, msg, Wh, Wl, bp, vA, vA, vH, N, 0, 1);

            // msg_f = Di @ v_out (gather vH)
            S = Sarena + 512 * sslot++;
            spmm_csr_kernel<<<RD / 4, 256, 0, stream>>>(ptrD, colsD, valsD, vH, msg, RD);
            stats_kernel<<<BF / 64, 256, 0, stream>>>(fA, msg, S, BF, 64, Fn, 0, 1);
            fold_kernel<<<128, 256, 0, stream>>>(S, g1, be1, Wl1, bl1, Wh, Wl, bp, 1.f / BF);
            gemm_mfma<<<BF / 128, 256, 0, stream>>>(fA, msg, Wh, Wl, bp, nullptr, fA, fH,
                                                    Fn, 0, 1);
        } else {
            for (int j = 0; j < 2; ++j) {
                const float* g = rn_gamma + (size_t)(i * 2 + j) * 256;
                const float* be = rn_beta + (size_t)(i * 2 + j) * 256;
                const float* Wlw = rn_W + (size_t)(i * 2 + j) * 256 * 128;
                const float* bl = rn_b + (size_t)(i * 2 + j) * 128;
                const float* src = (j == 0) ? vA : msg;
                float* dst = (j == 0) ? msg : vA;
                const float* resid = (j == 0) ? nullptr : vA;
                __half* shadow = (j == 0) ? nullptr : vH;

                float* S = Sarena + 512 * sslot++;
                float* avgacc = Aarena + 516 * aslot;
                float* masksum = avgacc + 512;
                aslot++;
                avgpool_kernel<<<dim3(N / 50, B), 128, 0, stream>>>(src, mask, avgacc,
                                                                    masksum, N, 50);
                finalize_avg<<<1, 128, 0, stream>>>(avgacc, masksum, avg, S, (float)N);
                stats_kernel<<<BN / 64, 128, 0, stream>>>(src, nullptr, S, BN, 64, N, 0, 0);
                fold_kernel<<<128, 256, 0, stream>>>(S, g, be, Wlw, bl, Wh, Wl, bp, 1.f / BN);
                gemm_mfma<<<BN / 128, 256, 0, stream>>>(src, avg, Wh, Wl, bp, resid, dst,
                                                        shadow, N, 1, 0);
            }
        }
    }

    float* S = Sarena + 512 * sslot++;
    stats_kernel<<<BF / 64, 128, 0, stream>>>(fA, nullptr, S, BF, 64, Fn, 0, 0);
    fold_final<<<1, 128, 0, stream>>>(S, g2, be2, W2, b2, W2p, 1.f / BF);
    final_out_kernel<<<BF / 4, 256, 0, stream>>>(fA, W2p, out);
}

// Round 6
// 5738.001 us; speedup vs baseline: 1.1661x; 1.1661x over previous
//
#include <hip/hip_runtime.h>
#include <hip/hip_fp16.h>
#include <math.h>

// DirModelToFace on MI355X — round 6:
//  * GEMM reverted to round-4 bf16 hi/lo 3-MFMA split (fp32 acc): fp16 single MFMA
//    failed accuracy (0.234 > 0.082; ~2^-11/layer compounds x16). Known-good 0.0156.
//  * spmm keeps round-5 restructure: packed int2 edges (one 8B load/edge), one dword
//    gather/edge (lane l reads all 4 batches x 32 fp16 ch as one 256B wave access),
//    4x manual unroll -> 4 gathers in flight (round-4 was latency-bound, 1.3k cyc/edge).

#define EPS 1e-5f

typedef float floatx4 __attribute__((ext_vector_type(4)));
typedef short shortx8 __attribute__((ext_vector_type(8)));

__device__ __forceinline__ float eluf(float x) { return x > 0.f ? x : expm1f(x); }
__device__ __forceinline__ float4 elu4(float4 v) {
    v.x = eluf(v.x); v.y = eluf(v.y); v.z = eluf(v.z); v.w = eluf(v.w); return v;
}
__device__ __forceinline__ short f2bf(float x) {  // round-to-nearest-even bf16
    unsigned u = __builtin_bit_cast(unsigned, x);
    u = u + 0x7FFFu + ((u >> 16) & 1u);
    return (short)(u >> 16);
}
__device__ __forceinline__ float bf2f(short h) {
    unsigned u = ((unsigned)(unsigned short)h) << 16;
    return __builtin_bit_cast(float, u);
}

// v = inputs @ W1 + b1; also fp16 shadow vH[(4*vert+(c>>5))*128 + b*32 + (c&31)]
__global__ void conv1_kernel(const float* __restrict__ in, const float* __restrict__ W1,
                             const float* __restrict__ b1, float* __restrict__ v,
                             __half* __restrict__ vH, int N) {
    int idx = blockIdx.x * 256 + threadIdx.x;
    int r = idx >> 7, c = idx & 127;
    float x0 = in[r * 3 + 0], x1 = in[r * 3 + 1], x2 = in[r * 3 + 2];
    float val = b1[c] + x0 * W1[c] + x1 * W1[128 + c] + x2 * W1[256 + c];
    v[(size_t)r * 128 + c] = val;
    int b = r / N, vert = r - b * N;
    vH[(size_t)(4 * vert + (c >> 5)) * 128 + b * 32 + (c & 31)] = __float2half(val);
}

// ---------------- CSR build ----------------

__global__ void hist_kernel(const int* __restrict__ rows, int* __restrict__ counts) {
    int e = blockIdx.x * 256 + threadIdx.x;
    atomicAdd(&counts[rows[e]], 1);
}

__global__ void partial_kernel(const int* __restrict__ counts, int* __restrict__ partials,
                               int R) {
    int t = threadIdx.x;
    int base = blockIdx.x * 1024 + t * 4;
    int s = 0;
#pragma unroll
    for (int j = 0; j < 4; ++j) { int i = base + j; if (i < R) s += counts[i]; }
    __shared__ int sh[256];
    sh[t] = s; __syncthreads();
    for (int st = 128; st > 0; st >>= 1) {
        if (t < st) sh[t] += sh[t + st];
        __syncthreads();
    }
    if (t == 0) partials[blockIdx.x] = sh[0];
}

__global__ void scanp_kernel(int* __restrict__ partials, int* __restrict__ rowptr,
                             int P, int R, int total) {
    __shared__ int sh[256];
    int t = threadIdx.x;
    int v = (t < P) ? partials[t] : 0;
    sh[t] = v; __syncthreads();
    for (int st = 1; st < 256; st <<= 1) {
        int tmp = (t >= st) ? sh[t - st] : 0;
        __syncthreads();
        sh[t] += tmp;
        __syncthreads();
    }
    if (t < P) partials[t] = sh[t] - v;
    if (t == 0) rowptr[R] = total;
}

__global__ void apply_kernel(int* __restrict__ counts, const int* __restrict__ partials,
                             int* __restrict__ rowptr, int R) {
    int t = threadIdx.x;
    int base = blockIdx.x * 1024 + t * 4;
    int c[4]; int s = 0;
#pragma unroll
    for (int j = 0; j < 4; ++j) { int i = base + j; c[j] = (i < R) ? counts[i] : 0; s += c[j]; }
    __shared__ int sh[256];
    sh[t] = s; __syncthreads();
    for (int st = 1; st < 256; st <<= 1) {
        int tmp = (t >= st) ? sh[t - st] : 0;
        __syncthreads();
        sh[t] += tmp;
        __syncthreads();
    }
    int off = partials[blockIdx.x] + sh[t] - s;
#pragma unroll
    for (int j = 0; j < 4; ++j) {
        int i = base + j;
        if (i < R) { rowptr[i] = off; counts[i] = off; }
        off += c[j];
    }
}

// pack {col, val_bits} so the spmm edge read is one 8B uniform load
__global__ void scatter_kernel(const int* __restrict__ rows, const int* __restrict__ cols,
                               const float* __restrict__ vals, int* __restrict__ fill,
                               int2* __restrict__ edges) {
    int e = blockIdx.x * 256 + threadIdx.x;
    int p = atomicAdd(&fill[rows[e]], 1);
    edges[p] = make_int2(cols[e], __float_as_int(vals[e]));
}

// ---------------- CSR spmm: 1 wave/row, 1 dword gather/edge, 4x unroll ----------------
// lane l: batch = l>>4, channel pair = l&15. Gather xH[co] = 256B blob, coalesced.
__global__ __launch_bounds__(256) void spmm_csr_kernel(
    const int* __restrict__ rowptr, const int2* __restrict__ edges,
    const __half2* __restrict__ xH, float* __restrict__ y, int R4) {
    int r = blockIdx.x * 4 + (threadIdx.x >> 6);
    int lane = threadIdx.x & 63;
    int b = lane >> 4, cp = lane & 15;
    const __half2* xb = xH + b * 16 + cp;
    int e0 = rowptr[r], e1 = rowptr[r + 1];
    float ax = 0.f, ay = 0.f;
    int e = e0;
    for (; e + 4 <= e1; e += 4) {
        int2 E0 = edges[e], E1 = edges[e + 1], E2 = edges[e + 2], E3 = edges[e + 3];
        __half2 g0 = xb[(size_t)E0.x * 64];
        __half2 g1 = xb[(size_t)E1.x * 64];
        __half2 g2 = xb[(size_t)E2.x * 64];
        __half2 g3 = xb[(size_t)E3.x * 64];
        float v0 = __int_as_float(E0.y), v1 = __int_as_float(E1.y);
        float v2 = __int_as_float(E2.y), v3 = __int_as_float(E3.y);
        float2 f0 = __half22float2(g0), f1 = __half22float2(g1);
        float2 f2 = __half22float2(g2), f3 = __half22float2(g3);
        ax += v0 * f0.x; ay += v0 * f0.y;
        ax += v1 * f1.x; ay += v1 * f1.y;
        ax += v2 * f2.x; ay += v2 * f2.y;
        ax += v3 * f3.x; ay += v3 * f3.y;
    }
    for (; e < e1; ++e) {
        int2 E = edges[e];
        __half2 g = xb[(size_t)E.x * 64];
        float v = __int_as_float(E.y);
        float2 f = __half22float2(g);
        ax += v * f.x; ay += v * f.y;
    }
    size_t rs = (size_t)R4 * 32;
    *(float2*)&y[(size_t)b * rs + (size_t)r * 32 + cp * 2] = make_float2(ax, ay);
}

// per-channel sums/sumsq over rows of X = [elu(A) | B-half]
__global__ void stats_kernel(const float* __restrict__ A, const float* __restrict__ Bs,
                             float* __restrict__ S, int R, int rpb, int rowsPerBatch,
                             int modeB, int eluB) {
    int t = threadIdx.x;
    int r0 = blockIdx.x * rpb;
    int r1 = min(r0 + rpb, R);
    float s1 = 0.f, s2 = 0.f;
    if (t < 128) {
        for (int r = r0; r < r1; ++r) {
            float v = eluf(A[(size_t)r * 128 + t]);
            s1 += v; s2 += v * v;
        }
    } else {
        int c = t - 128;
        if (modeB == 0) {
            for (int r = r0; r < r1; ++r) {
                float v = Bs[(size_t)r * 128 + c];
                if (eluB) v = eluf(v);
                s1 += v; s2 += v * v;
            }
        } else {
            for (int r = r0; r < r1; ++r) {
                float v = Bs[(r / rowsPerBatch) * 128 + c];
                s1 += v; s2 += v * v;
            }
        }
    }
    atomicAdd(&S[t], s1);
    atomicAdd(&S[256 + t], s2);
}

// Fold BN into weights; emit bf16 hi/lo split in [col][k] layout for MFMA B-frags.
__global__ void fold_kernel(const float* __restrict__ S, const float* __restrict__ gamma,
                            const float* __restrict__ beta, const float* __restrict__ W,
                            const float* __restrict__ bvec, short* __restrict__ Wh,
                            short* __restrict__ Wl, float* __restrict__ bp, float invR) {
    __shared__ float red[256];
    int o = blockIdx.x, k = threadIdx.x;
    float mean = S[k] * invR;
    float var = S[256 + k] * invR - mean * mean;
    float s = gamma[k] / sqrtf(var + EPS);
    float w = W[(size_t)k * 128 + o];
    float wp = s * w;
    short h = f2bf(wp);
    Wh[(size_t)o * 256 + k] = h;
    Wl[(size_t)o * 256 + k] = f2bf(wp - bf2f(h));
    red[k] = (beta[k] - mean * s) * w;
    __syncthreads();
    for (int st = 128; st > 0; st >>= 1) {
        if (k < st) red[k] += red[k + st];
        __syncthreads();
    }
    if (k == 0) bp[o] = bvec[o] + red[0];
}

// MFMA GEMM (bf16 hi/lo split, fp32 acc). Optional fp16 shadow write in epilogue.
__global__ __launch_bounds__(256) void gemm_mfma(
    const float* __restrict__ A, const float* __restrict__ Bs,
    const short* __restrict__ Wh, const short* __restrict__ Wl,
    const float* __restrict__ bp, const float* __restrict__ resid,
    float* __restrict__ out, __half* __restrict__ shadow,
    int rowsPerBatch, int modeB, int eluB) {
    const int lane = threadIdx.x & 63;
    const int wave = threadIdx.x >> 6;
    const int rowBase = blockIdx.x * 128 + wave * 32;
    const int m = lane & 15;
    const int kq = lane >> 4;
    floatx4 acc[2][8];
#pragma unroll
    for (int i = 0; i < 2; ++i)
#pragma unroll
        for (int j = 0; j < 8; ++j) acc[i][j] = {0.f, 0.f, 0.f, 0.f};

    for (int kb = 0; kb < 8; ++kb) {
        const int k0 = kb * 32 + kq * 8;
        shortx8 ah[2], al[2];
#pragma unroll
        for (int rg = 0; rg < 2; ++rg) {
            int row = rowBase + rg * 16 + m;
            float4 p, q;
            if (kb < 4) {
                p = elu4(*(const float4*)&A[(size_t)row * 128 + k0]);
                q = elu4(*(const float4*)&A[(size_t)row * 128 + k0 + 4]);
            } else {
                int kk = k0 - 128;
                if (modeB == 0) {
                    p = *(const float4*)&Bs[(size_t)row * 128 + kk];
                    q = *(const float4*)&Bs[(size_t)row * 128 + kk + 4];
                    if (eluB) { p = elu4(p); q = elu4(q); }
                } else {
                    int b = row / rowsPerBatch;
                    p = *(const float4*)&Bs[b * 128 + kk];
                    q = *(const float4*)&Bs[b * 128 + kk + 4];
                }
            }
            float x[8] = {p.x, p.y, p.z, p.w, q.x, q.y, q.z, q.w};
#pragma unroll
            for (int j = 0; j < 8; ++j) {
                short h = f2bf(x[j]);
                ah[rg][j] = h;
                al[rg][j] = f2bf(x[j] - bf2f(h));
            }
        }
#pragma unroll
        for (int ct = 0; ct < 8; ++ct) {
            shortx8 bh = *(const shortx8*)&Wh[(size_t)(ct * 16 + m) * 256 + k0];
            shortx8 bl = *(const shortx8*)&Wl[(size_t)(ct * 16 + m) * 256 + k0];
#pragma unroll
            for (int rg = 0; rg < 2; ++rg) {
                acc[rg][ct] = __builtin_amdgcn_mfma_f32_16x16x32_bf16(ah[rg], bh, acc[rg][ct], 0, 0, 0);
                acc[rg][ct] = __builtin_amdgcn_mfma_f32_16x16x32_bf16(ah[rg], bl, acc[rg][ct], 0, 0, 0);
                acc[rg][ct] = __builtin_amdgcn_mfma_f32_16x16x32_bf16(al[rg], bh, acc[rg][ct], 0, 0, 0);
            }
        }
    }
    // C/D layout col=lane&15, row=(lane>>4)*4+reg  [verified m89/m91]
#pragma unroll
    for (int ct = 0; ct < 8; ++ct) {
        int col = ct * 16 + m;
        float bb = bp[col];
#pragma unroll
        for (int rg = 0; rg < 2; ++rg) {
#pragma unroll
            for (int r = 0; r < 4; ++r) {
                int row = rowBase + rg * 16 + kq * 4 + r;
                size_t o = (size_t)row * 128 + col;
                float v = acc[rg][ct][r] + bb;
                if (resid) v += resid[o];
                out[o] = v;
                if (shadow) {
                    int b = row / rowsPerBatch, vert = row - b * rowsPerBatch;
                    shadow[(size_t)(4 * vert + (col >> 5)) * 128 + b * 32 + (col & 31)] =
                        __float2half(v);
                }
            }
        }
    }
}

// masked mean of elu(X): partial sums via atomics into pre-zeroed arena slot
__global__ void avgpool_kernel(const float* __restrict__ X, const float* __restrict__ mask,
                               float* __restrict__ avgacc, float* __restrict__ masksum,
                               int N, int rpb) {
    int b = blockIdx.y, t = threadIdx.x;
    int n0 = blockIdx.x * rpb;
    int n1 = min(n0 + rpb, N);
    float acc = 0.f, mac = 0.f;
    for (int n = n0; n < n1; ++n) {
        float m = mask[(size_t)b * N + n];
        float v = eluf(X[((size_t)b * N + n) * 128 + t]);
        acc += m * v;
        mac += m;
    }
    atomicAdd(&avgacc[b * 128 + t], acc);
    if (t == 0) atomicAdd(&masksum[b], mac);
}

__global__ void finalize_avg(const float* __restrict__ avgacc, const float* __restrict__ masksum,
                             float* __restrict__ avg, float* __restrict__ S, float fN) {
    int c = threadIdx.x;
    float s1 = 0.f, s2 = 0.f;
    for (int b = 0; b < 4; ++b) {
        float a = avgacc[b * 128 + c] / masksum[b];
        avg[b * 128 + c] = a;
        s1 += a; s2 += a * a;
    }
    S[128 + c] = s1 * fN;
    S[256 + 128 + c] = s2 * fN;
}

__global__ void fold_final(const float* __restrict__ S, const float* __restrict__ g2,
                           const float* __restrict__ be2, const float* __restrict__ W2,
                           const float* __restrict__ b2, float* __restrict__ W2p, float invR) {
    __shared__ float red[128];
    int c = threadIdx.x;
    float mean = S[c] * invR;
    float var = S[256 + c] * invR - mean * mean;
    float s = g2[c] / sqrtf(var + EPS);
    float w = W2[c];
    W2p[c] = s * w;
    red[c] = (be2[c] - mean * s) * w;
    __syncthreads();
    for (int st = 64; st > 0; st >>= 1) {
        if (c < st) red[c] += red[c + st];
        __syncthreads();
    }
    if (c == 0) W2p[128] = b2[0] + red[0];
}

__global__ void final_out_kernel(const float* __restrict__ f, const float* __restrict__ W2p,
                                 float* __restrict__ out) {
    int t = threadIdx.x;
    int w = t >> 6, lane = t & 63;
    int row = blockIdx.x * 4 + w;
    float a = eluf(f[(size_t)row * 128 + lane]) * W2p[lane] +
              eluf(f[(size_t)row * 128 + 64 + lane]) * W2p[64 + lane];
    for (int off = 32; off > 0; off >>= 1) a += __shfl_down(a, off);
    if (lane == 0) out[row] = a + W2p[128];
}

extern "C" void kernel_launch(void* const* d_in, const int* in_sizes, int n_in,
                              void* d_out, int out_size, void* d_ws, size_t ws_size,
                              hipStream_t stream) {
    const float* inputs = (const float*)d_in[0];
    const float* mask = (const float*)d_in[1];
    const int* Di_rows = (const int*)d_in[2];
    const int* Di_cols = (const int*)d_in[3];
    const float* Di_vals = (const float*)d_in[4];
    const int* DiA_rows = (const int*)d_in[5];
    const int* DiA_cols = (const int*)d_in[6];
    const float* DiA_vals = (const float*)d_in[7];
    const float* W1 = (const float*)d_in[8];
    const float* b1 = (const float*)d_in[9];
    const float* rn_gamma = (const float*)d_in[10];
    const float* rn_beta = (const float*)d_in[11];
    const float* rn_W = (const float*)d_in[12];
    const float* rn_b = (const float*)d_in[13];
    const float* g2 = (const float*)d_in[14];
    const float* be2 = (const float*)d_in[15];
    const float* W2 = (const float*)d_in[16];
    const float* b2 = (const float*)d_in[17];
    float* out = (float*)d_out;

    const int B = 4;
    const int BN = in_sizes[1];      // 48000
    const int N = BN / B;            // 12000
    const int BF = out_size;         // 96000
    const int Fn = BF / B;           // 24000
    const int nnz = in_sizes[2];     // 1,152,000
    const int RA = 4 * N;            // 48000
    const int RD = 4 * Fn;           // 96000

    float* ws = (float*)d_ws;
    size_t off = 0;
    float* vA = ws + off;  off += (size_t)BN * 128;
    float* fA = ws + off;  off += (size_t)BF * 128;
    float* msg = ws + off; off += (size_t)BF * 128;
    __half* vH = (__half*)(ws + off); off += (size_t)RA * 128 / 2;  // [r4][b][32] fp16
    __half* fH = (__half*)(ws + off); off += (size_t)RD * 128 / 2;
    int* ptrA    = (int*)(ws + off);  off += (size_t)RA + 4;
    int2* edgesA = (int2*)(ws + off); off += (size_t)nnz * 2;
    int* ptrD    = (int*)(ws + off);  off += (size_t)RD + 4;
    int2* edgesD = (int2*)(ws + off); off += (size_t)nnz * 2;
    int* tmpfill = (int*)(ws + off);  off += (size_t)RD;
    int* partials = (int*)(ws + off); off += 256;
    float* Sarena = ws + off; off += 33 * 512;   // pre-zeroed stats slots
    float* Aarena = ws + off; off += 16 * 516;   // pre-zeroed avgpool slots
    float* avg = ws + off;    off += 512;
    short* Wh = (short*)(ws + off); off += 128 * 256 / 2;
    short* Wl = (short*)(ws + off); off += 128 * 256 / 2;
    float* bp = ws + off;  off += 128;
    float* W2p = ws + off; off += 132;

    const int eBlocks = nnz / 256;
    const int PA = (RA + 1023) / 1024;
    const int PD = (RD + 1023) / 1024;

    hipMemsetAsync(Sarena, 0, (33 * 512 + 16 * 516) * 4, stream);
    hipMemsetAsync(fA, 0, (size_t)BF * 128 * 4, stream);
    hipMemsetAsync(fH, 0, (size_t)RD * 128 * 2, stream);

    // ---- build CSR for DiA ----
    hipMemsetAsync(tmpfill, 0, (size_t)RA * 4, stream);
    hist_kernel<<<eBlocks, 256, 0, stream>>>(DiA_rows, tmpfill);
    partial_kernel<<<PA, 256, 0, stream>>>(tmpfill, partials, RA);
    scanp_kernel<<<1, 256, 0, stream>>>(partials, ptrA, PA, RA, nnz);
    apply_kernel<<<PA, 256, 0, stream>>>(tmpfill, partials, ptrA, RA);
    scatter_kernel<<<eBlocks, 256, 0, stream>>>(DiA_rows, DiA_cols, DiA_vals, tmpfill, edgesA);
    // ---- build CSR for Di ----
    hipMemsetAsync(tmpfill, 0, (size_t)RD * 4, stream);
    hist_kernel<<<eBlocks, 256, 0, stream>>>(Di_rows, tmpfill);
    partial_kernel<<<PD, 256, 0, stream>>>(tmpfill, partials, RD);
    scanp_kernel<<<1, 256, 0, stream>>>(partials, ptrD, PD, RD, nnz);
    apply_kernel<<<PD, 256, 0, stream>>>(tmpfill, partials, ptrD, RD);
    scatter_kernel<<<eBlocks, 256, 0, stream>>>(Di_rows, Di_cols, Di_vals, tmpfill, edgesD);

    conv1_kernel<<<BN * 128 / 256, 256, 0, stream>>>(inputs, W1, b1, vA, vH, N);

    int sslot = 0, aslot = 0;
    for (int i = 0; i < 16; ++i) {
        if ((i & 1) == 0) {
            const float* g0 = rn_gamma + (size_t)(i * 2 + 0) * 256;
            const float* be0 = rn_beta + (size_t)(i * 2 + 0) * 256;
            const float* Wl0 = rn_W + (size_t)(i * 2 + 0) * 256 * 128;
            const float* bl0 = rn_b + (size_t)(i * 2 + 0) * 128;
            const float* g1 = rn_gamma + (size_t)(i * 2 + 1) * 256;
            const float* be1 = rn_beta + (size_t)(i * 2 + 1) * 256;
            const float* Wl1 = rn_W + (size_t)(i * 2 + 1) * 256 * 128;
            const float* bl1 = rn_b + (size_t)(i * 2 + 1) * 128;

            // msg_v = DiA @ f (gather fH)
            float* S = Sarena + 512 * sslot++;
            spmm_csr_kernel<<<RA / 4, 256, 0, stream>>>(ptrA, edgesA, (const __half2*)fH,
                                                        msg, RA);
            stats_kernel<<<BN / 64, 256, 0, stream>>>(vA, msg, S, BN, 64, N, 0, 1);
            fold_kernel<<<128, 256, 0, stream>>>(S, g0, be0, Wl0, bl0, Wh, Wl, bp, 1.f / BN);
            gemm_mfma<<<BN / 128, 256, 0, stream>>>(vA, msg, Wh, Wl, bp, vA, vA, vH, N, 0, 1);

            // msg_f = Di @ v_out (gather vH)
            S = Sarena + 512 * sslot++;
            spmm_csr_kernel<<<RD / 4, 256, 0, stream>>>(ptrD, edgesD, (const __half2*)vH,
                                                        msg, RD);
            stats_kernel<<<BF / 64, 256, 0, stream>>>(fA, msg, S, BF, 64, Fn, 0, 1);
            fold_kernel<<<128, 256, 0, stream>>>(S, g1, be1, Wl1, bl1, Wh, Wl, bp, 1.f / BF);
            gemm_mfma<<<BF / 128, 256, 0, stream>>>(fA, msg, Wh, Wl, bp, nullptr, fA, fH,
                                                    Fn, 0, 1);
        } else {
            for (int j = 0; j < 2; ++j) {
                const float* g = rn_gamma + (size_t)(i * 2 + j) * 256;
                const float* be = rn_beta + (size_t)(i * 2 + j) * 256;
                const float* Wlw = rn_W + (size_t)(i * 2 + j) * 256 * 128;
                const float* bl = rn_b + (size_t)(i * 2 + j) * 128;
                const float* src = (j == 0) ? vA : msg;
                float* dst = (j == 0) ? msg : vA;
                const float* resid = (j == 0) ? nullptr : vA;
                __half* shadow = (j == 0) ? nullptr : vH;

                float* S = Sarena + 512 * sslot++;
                float* avgacc = Aarena + 516 * aslot;
                float* masksum = avgacc + 512;
                aslot++;
                avgpool_kernel<<<dim3(N / 50, B), 128, 0, stream>>>(src, mask, avgacc,
                                                                    masksum, N, 50);
                finalize_avg<<<1, 128, 0, stream>>>(avgacc, masksum, avg, S, (float)N);
                stats_kernel<<<BN / 64, 128, 0, stream>>>(src, nullptr, S, BN, 64, N, 0, 0);
                fold_kernel<<<128, 256, 0, stream>>>(S, g, be, Wlw, bl, Wh, Wl, bp, 1.f / BN);
                gemm_mfma<<<BN / 128, 256, 0, stream>>>(src, avg, Wh, Wl, bp, resid, dst,
                                                        shadow, N, 1, 0);
            }
        }
    }

    float* S = Sarena + 512 * sslot++;
    stats_kernel<<<BF / 64, 128, 0, stream>>>(fA, nullptr, S, BF, 64, Fn, 0, 0);
    fold_final<<<1, 128, 0, stream>>>(S, g2, be2, W2, b2, W2p, 1.f / BF);
    final_out_kernel<<<BF / 4, 256, 0, stream>>>(fA, W2p, out);
}

// Round 7
// 5183.364 us; speedup vs baseline: 1.2909x; 1.1070x over previous
//
#include <hip/hip_runtime.h>
#include <hip/hip_fp16.h>
#include <math.h>

// DirModelToFace on MI355X — round 7:
//  * gemm_mfma: B-fragment loads (Wh/Wl) moved to LDS staging. Round-6 profile:
//    MfmaUtil 7%, VALUBusy 31%, 1.4TB/s -> latency-bound on per-lane B loads that
//    fragment into 16x64B L2 transactions each (128KB working set > L1). Now: per
//    K-slab, block stages 16KB coalesced into LDS (+8-short per-col pad -> worst
//    2-way bank aliasing = free), waves ds_read_b128 the frags. 20KB LDS/block.
//  * everything else unchanged from round 6 (bf16 hi/lo 3-MFMA split, CSR spmm
//    with packed edges + 1-dword/edge gather, arenas, fused BN fold).

#define EPS 1e-5f

typedef float floatx4 __attribute__((ext_vector_type(4)));
typedef short shortx8 __attribute__((ext_vector_type(8)));

__device__ __forceinline__ float eluf(float x) { return x > 0.f ? x : expm1f(x); }
__device__ __forceinline__ float4 elu4(float4 v) {
    v.x = eluf(v.x); v.y = eluf(v.y); v.z = eluf(v.z); v.w = eluf(v.w); return v;
}
__device__ __forceinline__ short f2bf(float x) {  // round-to-nearest-even bf16
    unsigned u = __builtin_bit_cast(unsigned, x);
    u = u + 0x7FFFu + ((u >> 16) & 1u);
    return (short)(u >> 16);
}
__device__ __forceinline__ float bf2f(short h) {
    unsigned u = ((unsigned)(unsigned short)h) << 16;
    return __builtin_bit_cast(float, u);
}

// v = inputs @ W1 + b1; also fp16 shadow vH[(4*vert+(c>>5))*128 + b*32 + (c&31)]
__global__ void conv1_kernel(const float* __restrict__ in, const float* __restrict__ W1,
                             const float* __restrict__ b1, float* __restrict__ v,
                             __half* __restrict__ vH, int N) {
    int idx = blockIdx.x * 256 + threadIdx.x;
    int r = idx >> 7, c = idx & 127;
    float x0 = in[r * 3 + 0], x1 = in[r * 3 + 1], x2 = in[r * 3 + 2];
    float val = b1[c] + x0 * W1[c] + x1 * W1[128 + c] + x2 * W1[256 + c];
    v[(size_t)r * 128 + c] = val;
    int b = r / N, vert = r - b * N;
    vH[(size_t)(4 * vert + (c >> 5)) * 128 + b * 32 + (c & 31)] = __float2half(val);
}

// ---------------- CSR build ----------------

__global__ void hist_kernel(const int* __restrict__ rows, int* __restrict__ counts) {
    int e = blockIdx.x * 256 + threadIdx.x;
    atomicAdd(&counts[rows[e]], 1);
}

__global__ void partial_kernel(const int* __restrict__ counts, int* __restrict__ partials,
                               int R) {
    int t = threadIdx.x;
    int base = blockIdx.x * 1024 + t * 4;
    int s = 0;
#pragma unroll
    for (int j = 0; j < 4; ++j) { int i = base + j; if (i < R) s += counts[i]; }
    __shared__ int sh[256];
    sh[t] = s; __syncthreads();
    for (int st = 128; st > 0; st >>= 1) {
        if (t < st) sh[t] += sh[t + st];
        __syncthreads();
    }
    if (t == 0) partials[blockIdx.x] = sh[0];
}

__global__ void scanp_kernel(int* __restrict__ partials, int* __restrict__ rowptr,
                             int P, int R, int total) {
    __shared__ int sh[256];
    int t = threadIdx.x;
    int v = (t < P) ? partials[t] : 0;
    sh[t] = v; __syncthreads();
    for (int st = 1; st < 256; st <<= 1) {
        int tmp = (t >= st) ? sh[t - st] : 0;
        __syncthreads();
        sh[t] += tmp;
        __syncthreads();
    }
    if (t < P) partials[t] = sh[t] - v;
    if (t == 0) rowptr[R] = total;
}

__global__ void apply_kernel(int* __restrict__ counts, const int* __restrict__ partials,
                             int* __restrict__ rowptr, int R) {
    int t = threadIdx.x;
    int base = blockIdx.x * 1024 + t * 4;
    int c[4]; int s = 0;
#pragma unroll
    for (int j = 0; j < 4; ++j) { int i = base + j; c[j] = (i < R) ? counts[i] : 0; s += c[j]; }
    __shared__ int sh[256];
    sh[t] = s; __syncthreads();
    for (int st = 1; st < 256; st <<= 1) {
        int tmp = (t >= st) ? sh[t - st] : 0;
        __syncthreads();
        sh[t] += tmp;
        __syncthreads();
    }
    int off = partials[blockIdx.x] + sh[t] - s;
#pragma unroll
    for (int j = 0; j < 4; ++j) {
        int i = base + j;
        if (i < R) { rowptr[i] = off; counts[i] = off; }
        off += c[j];
    }
}

// pack {col, val_bits} so the spmm edge read is one 8B uniform load
__global__ void scatter_kernel(const int* __restrict__ rows, const int* __restrict__ cols,
                               const float* __restrict__ vals, int* __restrict__ fill,
                               int2* __restrict__ edges) {
    int e = blockIdx.x * 256 + threadIdx.x;
    int p = atomicAdd(&fill[rows[e]], 1);
    edges[p] = make_int2(cols[e], __float_as_int(vals[e]));
}

// ---------------- CSR spmm: 1 wave/row, 1 dword gather/edge, 4x unroll ----------------
__global__ __launch_bounds__(256) void spmm_csr_kernel(
    const int* __restrict__ rowptr, const int2* __restrict__ edges,
    const __half2* __restrict__ xH, float* __restrict__ y, int R4) {
    int r = blockIdx.x * 4 + (threadIdx.x >> 6);
    int lane = threadIdx.x & 63;
    int b = lane >> 4, cp = lane & 15;
    const __half2* xb = xH + b * 16 + cp;
    int e0 = rowptr[r], e1 = rowptr[r + 1];
    float ax = 0.f, ay = 0.f;
    int e = e0;
    for (; e + 4 <= e1; e += 4) {
        int2 E0 = edges[e], E1 = edges[e + 1], E2 = edges[e + 2], E3 = edges[e + 3];
        __half2 g0 = xb[(size_t)E0.x * 64];
        __half2 g1 = xb[(size_t)E1.x * 64];
        __half2 g2 = xb[(size_t)E2.x * 64];
        __half2 g3 = xb[(size_t)E3.x * 64];
        float v0 = __int_as_float(E0.y), v1 = __int_as_float(E1.y);
        float v2 = __int_as_float(E2.y), v3 = __int_as_float(E3.y);
        float2 f0 = __half22float2(g0), f1 = __half22float2(g1);
        float2 f2 = __half22float2(g2), f3 = __half22float2(g3);
        ax += v0 * f0.x; ay += v0 * f0.y;
        ax += v1 * f1.x; ay += v1 * f1.y;
        ax += v2 * f2.x; ay += v2 * f2.y;
        ax += v3 * f3.x; ay += v3 * f3.y;
    }
    for (; e < e1; ++e) {
        int2 E = edges[e];
        __half2 g = xb[(size_t)E.x * 64];
        float v = __int_as_float(E.y);
        float2 f = __half22float2(g);
        ax += v * f.x; ay += v * f.y;
    }
    size_t rs = (size_t)R4 * 32;
    *(float2*)&y[(size_t)b * rs + (size_t)r * 32 + cp * 2] = make_float2(ax, ay);
}

// per-channel sums/sumsq over rows of X = [elu(A) | B-half]
__global__ void stats_kernel(const float* __restrict__ A, const float* __restrict__ Bs,
                             float* __restrict__ S, int R, int rpb, int rowsPerBatch,
                             int modeB, int eluB) {
    int t = threadIdx.x;
    int r0 = blockIdx.x * rpb;
    int r1 = min(r0 + rpb, R);
    float s1 = 0.f, s2 = 0.f;
    if (t < 128) {
        for (int r = r0; r < r1; ++r) {
            float v = eluf(A[(size_t)r * 128 + t]);
            s1 += v; s2 += v * v;
        }
    } else {
        int c = t - 128;
        if (modeB == 0) {
            for (int r = r0; r < r1; ++r) {
                float v = Bs[(size_t)r * 128 + c];
                if (eluB) v = eluf(v);
                s1 += v; s2 += v * v;
            }
        } else {
            for (int r = r0; r < r1; ++r) {
                float v = Bs[(r / rowsPerBatch) * 128 + c];
                s1 += v; s2 += v * v;
            }
        }
    }
    atomicAdd(&S[t], s1);
    atomicAdd(&S[256 + t], s2);
}

// Fold BN into weights; emit bf16 hi/lo split in [col][k] layout for MFMA B-frags.
__global__ void fold_kernel(const float* __restrict__ S, const float* __restrict__ gamma,
                            const float* __restrict__ beta, const float* __restrict__ W,
                            const float* __restrict__ bvec, short* __restrict__ Wh,
                            short* __restrict__ Wl, float* __restrict__ bp, float invR) {
    __shared__ float red[256];
    int o = blockIdx.x, k = threadIdx.x;
    float mean = S[k] * invR;
    float var = S[256 + k] * invR - mean * mean;
    float s = gamma[k] / sqrtf(var + EPS);
    float w = W[(size_t)k * 128 + o];
    float wp = s * w;
    short h = f2bf(wp);
    Wh[(size_t)o * 256 + k] = h;
    Wl[(size_t)o * 256 + k] = f2bf(wp - bf2f(h));
    red[k] = (beta[k] - mean * s) * w;
    __syncthreads();
    for (int st = 128; st > 0; st >>= 1) {
        if (k < st) red[k] += red[k + st];
        __syncthreads();
    }
    if (k == 0) bp[o] = bvec[o] + red[0];
}

// MFMA GEMM (bf16 hi/lo split, fp32 acc), B-frags staged through LDS per K-slab.
// LDS layout: [col][40 shorts] (32 data + 8 pad): bank base col*20 mod 32 spreads
// all banks; worst aliasing 2-way (free, m136).
__global__ __launch_bounds__(256) void gemm_mfma(
    const float* __restrict__ A, const float* __restrict__ Bs,
    const short* __restrict__ Wh, const short* __restrict__ Wl,
    const float* __restrict__ bp, const float* __restrict__ resid,
    float* __restrict__ out, __half* __restrict__ shadow,
    int rowsPerBatch, int modeB, int eluB) {
    __shared__ short Bsh[128 * 40];
    __shared__ short Bsl[128 * 40];
    const int t = threadIdx.x;
    const int lane = t & 63;
    const int wave = t >> 6;
    const int rowBase = blockIdx.x * 128 + wave * 32;
    const int m = lane & 15;
    const int kq = lane >> 4;
    floatx4 acc[2][8];
#pragma unroll
    for (int i = 0; i < 2; ++i)
#pragma unroll
        for (int j = 0; j < 8; ++j) acc[i][j] = {0.f, 0.f, 0.f, 0.f};

    for (int kb = 0; kb < 8; ++kb) {
        const int k0 = kb * 32 + kq * 8;
        __syncthreads();  // previous slab's LDS reads done
        // stage Wh/Wl K-slab: 128 cols x 32 k x 2B x2 = 16KB, coalesced 16B chunks
#pragma unroll
        for (int i = 0; i < 2; ++i) {
            int idx = t + 256 * i;
            int col = idx >> 2, q = idx & 3;
            shortx8 h = *(const shortx8*)&Wh[(size_t)col * 256 + kb * 32 + q * 8];
            shortx8 l = *(const shortx8*)&Wl[(size_t)col * 256 + kb * 32 + q * 8];
            *(shortx8*)&Bsh[col * 40 + q * 8] = h;
            *(shortx8*)&Bsl[col * 40 + q * 8] = l;
        }
        // A-frag load + elu + bf16 hi/lo split (overlaps staging latency)
        shortx8 ah[2], al[2];
#pragma unroll
        for (int rg = 0; rg < 2; ++rg) {
            int row = rowBase + rg * 16 + m;
            float4 p, q;
            if (kb < 4) {
                p = elu4(*(const float4*)&A[(size_t)row * 128 + k0]);
                q = elu4(*(const float4*)&A[(size_t)row * 128 + k0 + 4]);
            } else {
                int kk = k0 - 128;
                if (modeB == 0) {
                    p = *(const float4*)&Bs[(size_t)row * 128 + kk];
                    q = *(const float4*)&Bs[(size_t)row * 128 + kk + 4];
                    if (eluB) { p = elu4(p); q = elu4(q); }
                } else {
                    int b = row / rowsPerBatch;
                    p = *(const float4*)&Bs[b * 128 + kk];
                    q = *(const float4*)&Bs[b * 128 + kk + 4];
                }
            }
            float x[8] = {p.x, p.y, p.z, p.w, q.x, q.y, q.z, q.w};
#pragma unroll
            for (int j = 0; j < 8; ++j) {
                short h = f2bf(x[j]);
                ah[rg][j] = h;
                al[rg][j] = f2bf(x[j] - bf2f(h));
            }
        }
        __syncthreads();  // staging visible
#pragma unroll
        for (int ct = 0; ct < 8; ++ct) {
            int co = (ct * 16 + m) * 40 + kq * 8;
            shortx8 bh = *(const shortx8*)&Bsh[co];
            shortx8 bl = *(const shortx8*)&Bsl[co];
#pragma unroll
            for (int rg = 0; rg < 2; ++rg) {
                acc[rg][ct] = __builtin_amdgcn_mfma_f32_16x16x32_bf16(ah[rg], bh, acc[rg][ct], 0, 0, 0);
                acc[rg][ct] = __builtin_amdgcn_mfma_f32_16x16x32_bf16(ah[rg], bl, acc[rg][ct], 0, 0, 0);
                acc[rg][ct] = __builtin_amdgcn_mfma_f32_16x16x32_bf16(al[rg], bh, acc[rg][ct], 0, 0, 0);
            }
        }
    }
    // C/D layout col=lane&15, row=(lane>>4)*4+reg  [verified m89/m91]
#pragma unroll
    for (int ct = 0; ct < 8; ++ct) {
        int col = ct * 16 + m;
        float bb = bp[col];
#pragma unroll
        for (int rg = 0; rg < 2; ++rg) {
#pragma unroll
            for (int r = 0; r < 4; ++r) {
                int row = rowBase + rg * 16 + kq * 4 + r;
                size_t o = (size_t)row * 128 + col;
                float v = acc[rg][ct][r] + bb;
                if (resid) v += resid[o];
                out[o] = v;
                if (shadow) {
                    int b = row / rowsPerBatch, vert = row - b * rowsPerBatch;
                    shadow[(size_t)(4 * vert + (col >> 5)) * 128 + b * 32 + (col & 31)] =
                        __float2half(v);
                }
            }
        }
    }
}

// masked mean of elu(X): partial sums via atomics into pre-zeroed arena slot
__global__ void avgpool_kernel(const float* __restrict__ X, const float* __restrict__ mask,
                               float* __restrict__ avgacc, float* __restrict__ masksum,
                               int N, int rpb) {
    int b = blockIdx.y, t = threadIdx.x;
    int n0 = blockIdx.x * rpb;
    int n1 = min(n0 + rpb, N);
    float acc = 0.f, mac = 0.f;
    for (int n = n0; n < n1; ++n) {
        float m = mask[(size_t)b * N + n];
        float v = eluf(X[((size_t)b * N + n) * 128 + t]);
        acc += m * v;
        mac += m;
    }
    atomicAdd(&avgacc[b * 128 + t], acc);
    if (t == 0) atomicAdd(&masksum[b], mac);
}

__global__ void finalize_avg(const float* __restrict__ avgacc, const float* __restrict__ masksum,
                             float* __restrict__ avg, float* __restrict__ S, float fN) {
    int c = threadIdx.x;
    float s1 = 0.f, s2 = 0.f;
    for (int b = 0; b < 4; ++b) {
        float a = avgacc[b * 128 + c] / masksum[b];
        avg[b * 128 + c] = a;
        s1 += a; s2 += a * a;
    }
    S[128 + c] = s1 * fN;
    S[256 + 128 + c] = s2 * fN;
}

__global__ void fold_final(const float* __restrict__ S, const float* __restrict__ g2,
                           const float* __restrict__ be2, const float* __restrict__ W2,
                           const float* __restrict__ b2, float* __restrict__ W2p, float invR) {
    __shared__ float red[128];
    int c = threadIdx.x;
    float mean = S[c] * invR;
    float var = S[256 + c] * invR - mean * mean;
    float s = g2[c] / sqrtf(var + EPS);
    float w = W2[c];
    W2p[c] = s * w;
    red[c] = (be2[c] - mean * s) * w;
    __syncthreads();
    for (int st = 64; st > 0; st >>= 1) {
        if (c < st) red[c] += red[c + st];
        __syncthreads();
    }
    if (c == 0) W2p[128] = b2[0] + red[0];
}

__global__ void final_out_kernel(const float* __restrict__ f, const float* __restrict__ W2p,
                                 float* __restrict__ out) {
    int t = threadIdx.x;
    int w = t >> 6, lane = t & 63;
    int row = blockIdx.x * 4 + w;
    float a = eluf(f[(size_t)row * 128 + lane]) * W2p[lane] +
              eluf(f[(size_t)row * 128 + 64 + lane]) * W2p[64 + lane];
    for (int off = 32; off > 0; off >>= 1) a += __shfl_down(a, off);
    if (lane == 0) out[row] = a + W2p[128];
}

extern "C" void kernel_launch(void* const* d_in, const int* in_sizes, int n_in,
                              void* d_out, int out_size, void* d_ws, size_t ws_size,
                              hipStream_t stream) {
    const float* inputs = (const float*)d_in[0];
    const float* mask = (const float*)d_in[1];
    const int* Di_rows = (const int*)d_in[2];
    const int* Di_cols = (const int*)d_in[3];
    const float* Di_vals = (const float*)d_in[4];
    const int* DiA_rows = (const int*)d_in[5];
    const int* DiA_cols = (const int*)d_in[6];
    const float* DiA_vals = (const float*)d_in[7];
    const float* W1 = (const float*)d_in[8];
    const float* b1 = (const float*)d_in[9];
    const float* rn_gamma = (const float*)d_in[10];
    const float* rn_beta = (const float*)d_in[11];
    const float* rn_W = (const float*)d_in[12];
    const float* rn_b = (const float*)d_in[13];
    const float* g2 = (const float*)d_in[14];
    const float* be2 = (const float*)d_in[15];
    const float* W2 = (const float*)d_in[16];
    const float* b2 = (const float*)d_in[17];
    float* out = (float*)d_out;

    const int B = 4;
    const int BN = in_sizes[1];      // 48000
    const int N = BN / B;            // 12000
    const int BF = out_size;         // 96000
    const int Fn = BF / B;           // 24000
    const int nnz = in_sizes[2];     // 1,152,000
    const int RA = 4 * N;            // 48000
    const int RD = 4 * Fn;           // 96000

    float* ws = (float*)d_ws;
    size_t off = 0;
    float* vA = ws + off;  off += (size_t)BN * 128;
    float* fA = ws + off;  off += (size_t)BF * 128;
    float* msg = ws + off; off += (size_t)BF * 128;
    __half* vH = (__half*)(ws + off); off += (size_t)RA * 128 / 2;  // [r4][b][32] fp16
    __half* fH = (__half*)(ws + off); off += (size_t)RD * 128 / 2;
    int* ptrA    = (int*)(ws + off);  off += (size_t)RA + 4;
    int2* edgesA = (int2*)(ws + off); off += (size_t)nnz * 2;
    int* ptrD    = (int*)(ws + off);  off += (size_t)RD + 4;
    int2* edgesD = (int2*)(ws + off); off += (size_t)nnz * 2;
    int* tmpfill = (int*)(ws + off);  off += (size_t)RD;
    int* partials = (int*)(ws + off); off += 256;
    float* Sarena = ws + off; off += 33 * 512;   // pre-zeroed stats slots
    float* Aarena = ws + off; off += 16 * 516;   // pre-zeroed avgpool slots
    float* avg = ws + off;    off += 512;
    short* Wh = (short*)(ws + off); off += 128 * 256 / 2;
    short* Wl = (short*)(ws + off); off += 128 * 256 / 2;
    float* bp = ws + off;  off += 128;
    float* W2p = ws + off; off += 132;

    const int eBlocks = nnz / 256;
    const int PA = (RA + 1023) / 1024;
    const int PD = (RD + 1023) / 1024;

    hipMemsetAsync(Sarena, 0, (33 * 512 + 16 * 516) * 4, stream);
    hipMemsetAsync(fA, 0, (size_t)BF * 128 * 4, stream);
    hipMemsetAsync(fH, 0, (size_t)RD * 128 * 2, stream);

    // ---- build CSR for DiA ----
    hipMemsetAsync(tmpfill, 0, (size_t)RA * 4, stream);
    hist_kernel<<<eBlocks, 256, 0, stream>>>(DiA_rows, tmpfill);
    partial_kernel<<<PA, 256, 0, stream>>>(tmpfill, partials, RA);
    scanp_kernel<<<1, 256, 0, stream>>>(partials, ptrA, PA, RA, nnz);
    apply_kernel<<<PA, 256, 0, stream>>>(tmpfill, partials, ptrA, RA);
    scatter_kernel<<<eBlocks, 256, 0, stream>>>(DiA_rows, DiA_cols, DiA_vals, tmpfill, edgesA);
    // ---- build CSR for Di ----
    hipMemsetAsync(tmpfill, 0, (size_t)RD * 4, stream);
    hist_kernel<<<eBlocks, 256, 0, stream>>>(Di_rows, tmpfill);
    partial_kernel<<<PD, 256, 0, stream>>>(tmpfill, partials, RD);
    scanp_kernel<<<1, 256, 0, stream>>>(partials, ptrD, PD, RD, nnz);
    apply_kernel<<<PD, 256, 0, stream>>>(tmpfill, partials, ptrD, RD);
    scatter_kernel<<<eBlocks, 256, 0, stream>>>(Di_rows, Di_cols, Di_vals, tmpfill, edgesD);

    conv1_kernel<<<BN * 128 / 256, 256, 0, stream>>>(inputs, W1, b1, vA, vH, N);

    int sslot = 0, aslot = 0;
    for (int i = 0; i < 16; ++i) {
        if ((i & 1) == 0) {
            const float* g0 = rn_gamma + (size_t)(i * 2 + 0) * 256;
            const float* be0 = rn_beta + (size_t)(i * 2 + 0) * 256;
            const float* Wl0 = rn_W + (size_t)(i * 2 + 0) * 256 * 128;
            const float* bl0 = rn_b + (size_t)(i * 2 + 0) * 128;
            const float* g1 = rn_gamma + (size_t)(i * 2 + 1) * 256;
            const float* be1 = rn_beta + (size_t)(i * 2 + 1) * 256;
            const float* Wl1 = rn_W + (size_t)(i * 2 + 1) * 256 * 128;
            const float* bl1 = rn_b + (size_t)(i * 2 + 1) * 128;

            // msg_v = DiA @ f (gather fH)
            float* S = Sarena + 512 * sslot++;
            spmm_csr_kernel<<<RA / 4, 256, 0, stream>>>(ptrA, edgesA, (const __half2*)fH,
                                                        msg, RA);
            stats_kernel<<<BN / 64, 256, 0, stream>>>(vA, msg, S, BN, 64, N, 0, 1);
            fold_kernel<<<128, 256, 0, stream>>>(S, g0, be0, Wl0, bl0, Wh, Wl, bp, 1.f / BN);
            gemm_mfma<<<BN / 128, 256, 0, stream>>>(vA, msg, Wh, Wl, bp, vA, vA, vH, N, 0, 1);

            // msg_f = Di @ v_out (gather vH)
            S = Sarena + 512 * sslot++;
            spmm_csr_kernel<<<RD / 4, 256, 0, stream>>>(ptrD, edgesD, (const __half2*)vH,
                                                        msg, RD);
            stats_kernel<<<BF / 64, 256, 0, stream>>>(fA, msg, S, BF, 64, Fn, 0, 1);
            fold_kernel<<<128, 256, 0, stream>>>(S, g1, be1, Wl1, bl1, Wh, Wl, bp, 1.f / BF);
            gemm_mfma<<<BF / 128, 256, 0, stream>>>(fA, msg, Wh, Wl, bp, nullptr, fA, fH,
                                                    Fn, 0, 1);
        } else {
            for (int j = 0; j < 2; ++j) {
                const float* g = rn_gamma + (size_t)(i * 2 + j) * 256;
                const float* be = rn_beta + (size_t)(i * 2 + j) * 256;
                const float* Wlw = rn_W + (size_t)(i * 2 + j) * 256 * 128;
                const float* bl = rn_b + (size_t)(i * 2 + j) * 128;
                const float* src = (j == 0) ? vA : msg;
                float* dst = (j == 0) ? msg : vA;
                const float* resid = (j == 0) ? nullptr : vA;
                __half* shadow = (j == 0) ? nullptr : vH;

                float* S = Sarena + 512 * sslot++;
                float* avgacc = Aarena + 516 * aslot;
                float* masksum = avgacc + 512;
                aslot++;
                avgpool_kernel<<<dim3(N / 50, B), 128, 0, stream>>>(src, mask, avgacc,
                                                                    masksum, N, 50);
                finalize_avg<<<1, 128, 0, stream>>>(avgacc, masksum, avg, S, (float)N);
                stats_kernel<<<BN / 64, 128, 0, stream>>>(src, nullptr, S, BN, 64, N, 0, 0);
                fold_kernel<<<128, 256, 0, stream>>>(S, g, be, Wlw, bl, Wh, Wl, bp, 1.f / BN);
                gemm_mfma<<<BN / 128, 256, 0, stream>>>(src, avg, Wh, Wl, bp, resid, dst,
                                                        shadow, N, 1, 0);
            }
        }
    }

    float* S = Sarena + 512 * sslot++;
    stats_kernel<<<BF / 64, 128, 0, stream>>>(fA, nullptr, S, BF, 64, Fn, 0, 0);
    fold_final<<<1, 128, 0, stream>>>(S, g2, be2, W2, b2, W2p, 1.f / BF);
    final_out_kernel<<<BF / 4, 256, 0, stream>>>(fA, W2p, out);
}

// Round 9
// 4952.658 us; speedup vs baseline: 1.3510x; 1.0466x over previous
//
#include <hip/hip_runtime.h>
#include <hip/hip_fp16.h>
#include <math.h>

// DirModelToFace on MI355X — round 9 (round-8 fix):
//  * BUGFIX: spmm fused B-half stats must index channel (r&3)*32 + c32 (msg is
//    [b][4*vert+q][32] = [b][vert][q*32+c]); round 8 folded all q into ch 0-31 ->
//    negative var -> sqrt(NaN). Now 4 per-q accumulator sets (q = rr&3).
//  * rest as round 8: BN stats fused into producer epilogues (conv1/gemm A-half,
//    spmm B-half, finalize_avg broadcast-half); dead layer 15 removed; 8 rows/wave
//    spmm; bf16 hi/lo 3-MFMA GEMM with LDS-staged B; CSR build with packed edges.

#define EPS 1e-5f

typedef float floatx4 __attribute__((ext_vector_type(4)));
typedef short shortx8 __attribute__((ext_vector_type(8)));

__device__ __forceinline__ float eluf(float x) { return x > 0.f ? x : expm1f(x); }
__device__ __forceinline__ float4 elu4(float4 v) {
    v.x = eluf(v.x); v.y = eluf(v.y); v.z = eluf(v.z); v.w = eluf(v.w); return v;
}
__device__ __forceinline__ short f2bf(float x) {  // round-to-nearest-even bf16
    unsigned u = __builtin_bit_cast(unsigned, x);
    u = u + 0x7FFFu + ((u >> 16) & 1u);
    return (short)(u >> 16);
}
__device__ __forceinline__ float bf2f(short h) {
    unsigned u = ((unsigned)(unsigned short)h) << 16;
    return __builtin_bit_cast(float, u);
}

// v = inputs @ W1 + b1; fp16 shadow; fused elu-stats (A-half of dir0 slot0).
__global__ void conv1_kernel(const float* __restrict__ in, const float* __restrict__ W1,
                             const float* __restrict__ b1, float* __restrict__ v,
                             __half* __restrict__ vH, int N, float* __restrict__ Sout) {
    int t = threadIdx.x;
    int c = t & 127, half = t >> 7;
    int r0 = blockIdx.x * 64;
    float w0 = W1[c], w1 = W1[128 + c], w2 = W1[256 + c], bb = b1[c];
    float s1 = 0.f, s2 = 0.f;
    for (int k = 0; k < 32; ++k) {
        int r = r0 + half + 2 * k;
        float x0 = in[r * 3 + 0], x1 = in[r * 3 + 1], x2 = in[r * 3 + 2];
        float val = bb + x0 * w0 + x1 * w1 + x2 * w2;
        v[(size_t)r * 128 + c] = val;
        int b = r / N, vert = r - b * N;
        vH[(size_t)(4 * vert + (c >> 5)) * 128 + b * 32 + (c & 31)] = __float2half(val);
        float e = eluf(val);
        s1 += e; s2 += e * e;
    }
    atomicAdd(&Sout[c], s1);
    atomicAdd(&Sout[256 + c], s2);
}

// ---------------- CSR build ----------------

__global__ void hist_kernel(const int* __restrict__ rows, int* __restrict__ counts) {
    int e = blockIdx.x * 256 + threadIdx.x;
    atomicAdd(&counts[rows[e]], 1);
}

__global__ void partial_kernel(const int* __restrict__ counts, int* __restrict__ partials,
                               int R) {
    int t = threadIdx.x;
    int base = blockIdx.x * 1024 + t * 4;
    int s = 0;
#pragma unroll
    for (int j = 0; j < 4; ++j) { int i = base + j; if (i < R) s += counts[i]; }
    __shared__ int sh[256];
    sh[t] = s; __syncthreads();
    for (int st = 128; st > 0; st >>= 1) {
        if (t < st) sh[t] += sh[t + st];
        __syncthreads();
    }
    if (t == 0) partials[blockIdx.x] = sh[0];
}

__global__ void scanp_kernel(int* __restrict__ partials, int* __restrict__ rowptr,
                             int P, int R, int total) {
    __shared__ int sh[256];
    int t = threadIdx.x;
    int v = (t < P) ? partials[t] : 0;
    sh[t] = v; __syncthreads();
    for (int st = 1; st < 256; st <<= 1) {
        int tmp = (t >= st) ? sh[t - st] : 0;
        __syncthreads();
        sh[t] += tmp;
        __syncthreads();
    }
    if (t < P) partials[t] = sh[t] - v;
    if (t == 0) rowptr[R] = total;
}

__global__ void apply_kernel(int* __restrict__ counts, const int* __restrict__ partials,
                             int* __restrict__ rowptr, int R) {
    int t = threadIdx.x;
    int base = blockIdx.x * 1024 + t * 4;
    int c[4]; int s = 0;
#pragma unroll
    for (int j = 0; j < 4; ++j) { int i = base + j; c[j] = (i < R) ? counts[i] : 0; s += c[j]; }
    __shared__ int sh[256];
    sh[t] = s; __syncthreads();
    for (int st = 1; st < 256; st <<= 1) {
        int tmp = (t >= st) ? sh[t - st] : 0;
        __syncthreads();
        sh[t] += tmp;
        __syncthreads();
    }
    int off = partials[blockIdx.x] + sh[t] - s;
#pragma unroll
    for (int j = 0; j < 4; ++j) {
        int i = base + j;
        if (i < R) { rowptr[i] = off; counts[i] = off; }
        off += c[j];
    }
}

__global__ void scatter_kernel(const int* __restrict__ rows, const int* __restrict__ cols,
                               const float* __restrict__ vals, int* __restrict__ fill,
                               int2* __restrict__ edges) {
    int e = blockIdx.x * 256 + threadIdx.x;
    int p = atomicAdd(&fill[rows[e]], 1);
    edges[p] = make_int2(cols[e], __float_as_int(vals[e]));
}

// ---------------- CSR spmm: 8 rows/wave, 1 dword gather/edge, fused B-half stats ----
// lane l: batch = l>>4, channel pair cp = l&15. Flat msg channel = (r&3)*32 + cp*2.
__global__ __launch_bounds__(256) void spmm_csr_kernel(
    const int* __restrict__ rowptr, const int2* __restrict__ edges,
    const __half2* __restrict__ xH, float* __restrict__ y, int R4,
    float* __restrict__ Sout) {
    int t = threadIdx.x;
    int waveId = blockIdx.x * 4 + (t >> 6);
    int lane = t & 63;
    int b = lane >> 4, cp = lane & 15;
    const __half2* xb = xH + b * 16 + cp;
    size_t rs = (size_t)R4 * 32;
    float s1a[4], s2a[4], s1b[4], s2b[4];
#pragma unroll
    for (int q = 0; q < 4; ++q) { s1a[q] = 0.f; s2a[q] = 0.f; s1b[q] = 0.f; s2b[q] = 0.f; }
    for (int rr = 0; rr < 8; ++rr) {
        int r = waveId * 8 + rr;
        int q = rr & 3;   // == r & 3 (waveId*8 is a multiple of 4)
        int e0 = rowptr[r], e1 = rowptr[r + 1];
        float ax = 0.f, ay = 0.f;
        int e = e0;
        for (; e + 4 <= e1; e += 4) {
            int2 E0 = edges[e], E1 = edges[e + 1], E2 = edges[e + 2], E3 = edges[e + 3];
            __half2 g0 = xb[(size_t)E0.x * 64];
            __half2 g1 = xb[(size_t)E1.x * 64];
            __half2 g2 = xb[(size_t)E2.x * 64];
            __half2 g3 = xb[(size_t)E3.x * 64];
            float v0 = __int_as_float(E0.y), v1 = __int_as_float(E1.y);
            float v2 = __int_as_float(E2.y), v3 = __int_as_float(E3.y);
            float2 f0 = __half22float2(g0), f1 = __half22float2(g1);
            float2 f2 = __half22float2(g2), f3 = __half22float2(g3);
            ax += v0 * f0.x; ay += v0 * f0.y;
            ax += v1 * f1.x; ay += v1 * f1.y;
            ax += v2 * f2.x; ay += v2 * f2.y;
            ax += v3 * f3.x; ay += v3 * f3.y;
        }
        for (; e < e1; ++e) {
            int2 E = edges[e];
            __half2 g = xb[(size_t)E.x * 64];
            float v = __int_as_float(E.y);
            float2 f = __half22float2(g);
            ax += v * f.x; ay += v * f.y;
        }
        *(float2*)&y[(size_t)b * rs + (size_t)r * 32 + cp * 2] = make_float2(ax, ay);
        float ea = eluf(ax), eb = eluf(ay);
        s1a[q] += ea; s2a[q] += ea * ea;
        s1b[q] += eb; s2b[q] += eb * eb;
    }
    // butterfly over batch lanes (bits 4,5), per q; then LDS merge across waves
    __shared__ float red[256];
    red[t] = 0.f;
    __syncthreads();
#pragma unroll
    for (int q = 0; q < 4; ++q) {
        s1a[q] += __shfl_xor(s1a[q], 16); s1a[q] += __shfl_xor(s1a[q], 32);
        s2a[q] += __shfl_xor(s2a[q], 16); s2a[q] += __shfl_xor(s2a[q], 32);
        s1b[q] += __shfl_xor(s1b[q], 16); s1b[q] += __shfl_xor(s1b[q], 32);
        s2b[q] += __shfl_xor(s2b[q], 16); s2b[q] += __shfl_xor(s2b[q], 32);
    }
    if (lane < 16) {
#pragma unroll
        for (int q = 0; q < 4; ++q) {
            int ch = q * 32 + cp * 2;
            atomicAdd(&red[ch], s1a[q]);
            atomicAdd(&red[ch + 1], s1b[q]);
            atomicAdd(&red[128 + ch], s2a[q]);
            atomicAdd(&red[128 + ch + 1], s2b[q]);
        }
    }
    __syncthreads();
    if (t < 128) atomicAdd(&Sout[128 + t], red[t]);
    else atomicAdd(&Sout[384 + (t - 128)], red[t]);
}

// Fold BN into weights; emit bf16 hi/lo split in [col][k] layout for MFMA B-frags.
__global__ void fold_kernel(const float* __restrict__ S, const float* __restrict__ gamma,
                            const float* __restrict__ beta, const float* __restrict__ W,
                            const float* __restrict__ bvec, short* __restrict__ Wh,
                            short* __restrict__ Wl, float* __restrict__ bp, float invR) {
    __shared__ float red[256];
    int o = blockIdx.x, k = threadIdx.x;
    float mean = S[k] * invR;
    float var = S[256 + k] * invR - mean * mean;
    float s = gamma[k] / sqrtf(var + EPS);
    float w = W[(size_t)k * 128 + o];
    float wp = s * w;
    short h = f2bf(wp);
    Wh[(size_t)o * 256 + k] = h;
    Wl[(size_t)o * 256 + k] = f2bf(wp - bf2f(h));
    red[k] = (beta[k] - mean * s) * w;
    __syncthreads();
    for (int st = 128; st > 0; st >>= 1) {
        if (k < st) red[k] += red[k + st];
        __syncthreads();
    }
    if (k == 0) bp[o] = bvec[o] + red[0];
}

// MFMA GEMM (bf16 hi/lo split, fp32 acc), LDS-staged B, fused elu-stats epilogue.
__global__ __launch_bounds__(256) void gemm_mfma(
    const float* __restrict__ A, const float* __restrict__ Bs,
    const short* __restrict__ Wh, const short* __restrict__ Wl,
    const float* __restrict__ bp, const float* __restrict__ resid,
    float* __restrict__ out, __half* __restrict__ shadow,
    float* __restrict__ Sout, int rowsPerBatch, int modeB, int eluB) {
    __shared__ short Bsh[128 * 40];
    __shared__ short Bsl[128 * 40];
    const int t = threadIdx.x;
    const int lane = t & 63;
    const int wave = t >> 6;
    const int rowBase = blockIdx.x * 128 + wave * 32;
    const int m = lane & 15;
    const int kq = lane >> 4;
    floatx4 acc[2][8];
#pragma unroll
    for (int i = 0; i < 2; ++i)
#pragma unroll
        for (int j = 0; j < 8; ++j) acc[i][j] = {0.f, 0.f, 0.f, 0.f};

    for (int kb = 0; kb < 8; ++kb) {
        const int k0 = kb * 32 + kq * 8;
        __syncthreads();
#pragma unroll
        for (int i = 0; i < 2; ++i) {
            int idx = t + 256 * i;
            int col = idx >> 2, q = idx & 3;
            shortx8 h = *(const shortx8*)&Wh[(size_t)col * 256 + kb * 32 + q * 8];
            shortx8 l = *(const shortx8*)&Wl[(size_t)col * 256 + kb * 32 + q * 8];
            *(shortx8*)&Bsh[col * 40 + q * 8] = h;
            *(shortx8*)&Bsl[col * 40 + q * 8] = l;
        }
        shortx8 ah[2], al[2];
#pragma unroll
        for (int rg = 0; rg < 2; ++rg) {
            int row = rowBase + rg * 16 + m;
            float4 p, q;
            if (kb < 4) {
                p = elu4(*(const float4*)&A[(size_t)row * 128 + k0]);
                q = elu4(*(const float4*)&A[(size_t)row * 128 + k0 + 4]);
            } else {
                int kk = k0 - 128;
                if (modeB == 0) {
                    p = *(const float4*)&Bs[(size_t)row * 128 + kk];
                    q = *(const float4*)&Bs[(size_t)row * 128 + kk + 4];
                    if (eluB) { p = elu4(p); q = elu4(q); }
                } else {
                    int b = row / rowsPerBatch;
                    p = *(const float4*)&Bs[b * 128 + kk];
                    q = *(const float4*)&Bs[b * 128 + kk + 4];
                }
            }
            float x[8] = {p.x, p.y, p.z, p.w, q.x, q.y, q.z, q.w};
#pragma unroll
            for (int j = 0; j < 8; ++j) {
                short h = f2bf(x[j]);
                ah[rg][j] = h;
                al[rg][j] = f2bf(x[j] - bf2f(h));
            }
        }
        __syncthreads();
#pragma unroll
        for (int ct = 0; ct < 8; ++ct) {
            int co = (ct * 16 + m) * 40 + kq * 8;
            shortx8 bh = *(const shortx8*)&Bsh[co];
            shortx8 bl = *(const shortx8*)&Bsl[co];
#pragma unroll
            for (int rg = 0; rg < 2; ++rg) {
                acc[rg][ct] = __builtin_amdgcn_mfma_f32_16x16x32_bf16(ah[rg], bh, acc[rg][ct], 0, 0, 0);
                acc[rg][ct] = __builtin_amdgcn_mfma_f32_16x16x32_bf16(ah[rg], bl, acc[rg][ct], 0, 0, 0);
                acc[rg][ct] = __builtin_amdgcn_mfma_f32_16x16x32_bf16(al[rg], bh, acc[rg][ct], 0, 0, 0);
            }
        }
    }
    // epilogue: C/D layout col=lane&15, row=(lane>>4)*4+reg  [verified m89/m91]
    float cs1[8], cs2[8];
#pragma unroll
    for (int ct = 0; ct < 8; ++ct) { cs1[ct] = 0.f; cs2[ct] = 0.f; }
#pragma unroll
    for (int ct = 0; ct < 8; ++ct) {
        int col = ct * 16 + m;
        float bb = bp[col];
#pragma unroll
        for (int rg = 0; rg < 2; ++rg) {
#pragma unroll
            for (int r = 0; r < 4; ++r) {
                int row = rowBase + rg * 16 + kq * 4 + r;
                size_t o = (size_t)row * 128 + col;
                float v = acc[rg][ct][r] + bb;
                if (resid) v += resid[o];
                out[o] = v;
                if (shadow) {
                    int b = row / rowsPerBatch, vert = row - b * rowsPerBatch;
                    shadow[(size_t)(4 * vert + (col >> 5)) * 128 + b * 32 + (col & 31)] =
                        __float2half(v);
                }
                float e = eluf(v);
                cs1[ct] += e; cs2[ct] += e * e;
            }
        }
    }
    if (Sout) {  // fused elu-stats for the consuming layer's BN (A-half)
        __syncthreads();           // all waves done with Bsh
        float* red = (float*)Bsh;  // 256 floats
        red[t] = 0.f;
        __syncthreads();
#pragma unroll
        for (int ct = 0; ct < 8; ++ct) {
            cs1[ct] += __shfl_xor(cs1[ct], 16); cs1[ct] += __shfl_xor(cs1[ct], 32);
            cs2[ct] += __shfl_xor(cs2[ct], 16); cs2[ct] += __shfl_xor(cs2[ct], 32);
        }
        if (kq == 0) {
#pragma unroll
            for (int ct = 0; ct < 8; ++ct) {
                atomicAdd(&red[ct * 16 + m], cs1[ct]);
                atomicAdd(&red[128 + ct * 16 + m], cs2[ct]);
            }
        }
        __syncthreads();
        if (t < 128) atomicAdd(&Sout[t], red[t]);
        else atomicAdd(&Sout[256 + (t - 128)], red[t]);
    }
}

// masked mean of elu(X): partial sums via atomics into pre-zeroed arena slot
__global__ void avgpool_kernel(const float* __restrict__ X, const float* __restrict__ mask,
                               float* __restrict__ avgacc, float* __restrict__ masksum,
                               int N, int rpb) {
    int b = blockIdx.y, t = threadIdx.x;
    int n0 = blockIdx.x * rpb;
    int n1 = min(n0 + rpb, N);
    float acc = 0.f, mac = 0.f;
    for (int n = n0; n < n1; ++n) {
        float m = mask[(size_t)b * N + n];
        float v = eluf(X[((size_t)b * N + n) * 128 + t]);
        acc += m * v;
        mac += m;
    }
    atomicAdd(&avgacc[b * 128 + t], acc);
    if (t == 0) atomicAdd(&masksum[b], mac);
}

__global__ void finalize_avg(const float* __restrict__ avgacc, const float* __restrict__ masksum,
                             float* __restrict__ avg, float* __restrict__ S, float fN) {
    int c = threadIdx.x;
    float s1 = 0.f, s2 = 0.f;
    for (int b = 0; b < 4; ++b) {
        float a = avgacc[b * 128 + c] / masksum[b];
        avg[b * 128 + c] = a;
        s1 += a; s2 += a * a;
    }
    S[128 + c] = s1 * fN;
    S[256 + 128 + c] = s2 * fN;
}

__global__ void fold_final(const float* __restrict__ S, const float* __restrict__ g2,
                           const float* __restrict__ be2, const float* __restrict__ W2,
                           const float* __restrict__ b2, float* __restrict__ W2p, float invR) {
    __shared__ float red[128];
    int c = threadIdx.x;
    float mean = S[c] * invR;
    float var = S[256 + c] * invR - mean * mean;
    float s = g2[c] / sqrtf(var + EPS);
    float w = W2[c];
    W2p[c] = s * w;
    red[c] = (be2[c] - mean * s) * w;
    __syncthreads();
    for (int st = 64; st > 0; st >>= 1) {
        if (c < st) red[c] += red[c + st];
        __syncthreads();
    }
    if (c == 0) W2p[128] = b2[0] + red[0];
}

__global__ void final_out_kernel(const float* __restrict__ f, const float* __restrict__ W2p,
                                 float* __restrict__ out) {
    int t = threadIdx.x;
    int w = t >> 6, lane = t & 63;
    int row = blockIdx.x * 4 + w;
    float a = eluf(f[(size_t)row * 128 + lane]) * W2p[lane] +
              eluf(f[(size_t)row * 128 + 64 + lane]) * W2p[64 + lane];
    for (int off = 32; off > 0; off >>= 1) a += __shfl_down(a, off);
    if (lane == 0) out[row] = a + W2p[128];
}

extern "C" void kernel_launch(void* const* d_in, const int* in_sizes, int n_in,
                              void* d_out, int out_size, void* d_ws, size_t ws_size,
                              hipStream_t stream) {
    const float* inputs = (const float*)d_in[0];
    const float* mask = (const float*)d_in[1];
    const int* Di_rows = (const int*)d_in[2];
    const int* Di_cols = (const int*)d_in[3];
    const float* Di_vals = (const float*)d_in[4];
    const int* DiA_rows = (const int*)d_in[5];
    const int* DiA_cols = (const int*)d_in[6];
    const float* DiA_vals = (const float*)d_in[7];
    const float* W1 = (const float*)d_in[8];
    const float* b1 = (const float*)d_in[9];
    const float* rn_gamma = (const float*)d_in[10];
    const float* rn_beta = (const float*)d_in[11];
    const float* rn_W = (const float*)d_in[12];
    const float* rn_b = (const float*)d_in[13];
    const float* g2 = (const float*)d_in[14];
    const float* be2 = (const float*)d_in[15];
    const float* W2 = (const float*)d_in[16];
    const float* b2 = (const float*)d_in[17];
    float* out = (float*)d_out;

    const int B = 4;
    const int BN = in_sizes[1];      // 48000
    const int N = BN / B;            // 12000
    const int BF = out_size;         // 96000
    const int Fn = BF / B;           // 24000
    const int nnz = in_sizes[2];     // 1,152,000
    const int RA = 4 * N;            // 48000
    const int RD = 4 * Fn;           // 96000

    float* ws = (float*)d_ws;
    size_t off = 0;
    float* vA = ws + off;  off += (size_t)BN * 128;
    float* fA = ws + off;  off += (size_t)BF * 128;
    float* msg = ws + off; off += (size_t)BF * 128;
    __half* vH = (__half*)(ws + off); off += (size_t)RA * 128 / 2;  // [r4][b][32] fp16
    __half* fH = (__half*)(ws + off); off += (size_t)RD * 128 / 2;
    int* ptrA    = (int*)(ws + off);  off += (size_t)RA + 4;
    int2* edgesA = (int2*)(ws + off); off += (size_t)nnz * 2;
    int* ptrD    = (int*)(ws + off);  off += (size_t)RD + 4;
    int2* edgesD = (int2*)(ws + off); off += (size_t)nnz * 2;
    int* tmpfill = (int*)(ws + off);  off += (size_t)RD;
    int* partials = (int*)(ws + off); off += 256;
    float* Sarena = ws + off; off += 33 * 512;   // pre-zeroed stats slots (2i+j map)
    float* Aarena = ws + off; off += 16 * 516;   // pre-zeroed avgpool slots
    float* avg = ws + off;    off += 512;
    short* Wh = (short*)(ws + off); off += 128 * 256 / 2;
    short* Wl = (short*)(ws + off); off += 128 * 256 / 2;
    float* bp = ws + off;  off += 128;
    float* W2p = ws + off; off += 132;

    const int eBlocks = nnz / 256;
    const int PA = (RA + 1023) / 1024;
    const int PD = (RD + 1023) / 1024;

    hipMemsetAsync(Sarena, 0, (33 * 512 + 16 * 516) * 4, stream);
    hipMemsetAsync(fA, 0, (size_t)BF * 128 * 4, stream);
    hipMemsetAsync(fH, 0, (size_t)RD * 128 * 2, stream);

    // ---- build CSR for DiA ----
    hipMemsetAsync(tmpfill, 0, (size_t)RA * 4, stream);
    hist_kernel<<<eBlocks, 256, 0, stream>>>(DiA_rows, tmpfill);
    partial_kernel<<<PA, 256, 0, stream>>>(tmpfill, partials, RA);
    scanp_kernel<<<1, 256, 0, stream>>>(partials, ptrA, PA, RA, nnz);
    apply_kernel<<<PA, 256, 0, stream>>>(tmpfill, partials, ptrA, RA);
    scatter_kernel<<<eBlocks, 256, 0, stream>>>(DiA_rows, DiA_cols, DiA_vals, tmpfill, edgesA);
    // ---- build CSR for Di ----
    hipMemsetAsync(tmpfill, 0, (size_t)RD * 4, stream);
    hist_kernel<<<eBlocks, 256, 0, stream>>>(Di_rows, tmpfill);
    partial_kernel<<<PD, 256, 0, stream>>>(tmpfill, partials, RD);
    scanp_kernel<<<1, 256, 0, stream>>>(partials, ptrD, PD, RD, nnz);
    apply_kernel<<<PD, 256, 0, stream>>>(tmpfill, partials, ptrD, RD);
    scatter_kernel<<<eBlocks, 256, 0, stream>>>(Di_rows, Di_cols, Di_vals, tmpfill, edgesD);

    // S slot map: conv layer (i,j) -> Sarena + 512*(2i+j); final conv -> slot 32
    auto slot = [&](int i, int j) { return Sarena + 512 * (2 * i + j); };
    float* Sfinal = Sarena + 512 * 32;

    conv1_kernel<<<BN / 64, 256, 0, stream>>>(inputs, W1, b1, vA, vH, N, slot(0, 0));

    int aslot = 0;
    for (int i = 0; i < 15; ++i) {   // layer 15 (avg) is dead: output depends only on f
        if ((i & 1) == 0) {
            const float* g0 = rn_gamma + (size_t)(i * 2 + 0) * 256;
            const float* be0 = rn_beta + (size_t)(i * 2 + 0) * 256;
            const float* Wl0 = rn_W + (size_t)(i * 2 + 0) * 256 * 128;
            const float* bl0 = rn_b + (size_t)(i * 2 + 0) * 128;
            const float* g1 = rn_gamma + (size_t)(i * 2 + 1) * 256;
            const float* be1 = rn_beta + (size_t)(i * 2 + 1) * 256;
            const float* Wl1 = rn_W + (size_t)(i * 2 + 1) * 256 * 128;
            const float* bl1 = rn_b + (size_t)(i * 2 + 1) * 128;

            // msg_v = DiA @ f (gather fH); B-half stats -> slot(i,0)
            spmm_csr_kernel<<<RA / 32, 256, 0, stream>>>(ptrA, edgesA, (const __half2*)fH,
                                                         msg, RA, slot(i, 0));
            fold_kernel<<<128, 256, 0, stream>>>(slot(i, 0), g0, be0, Wl0, bl0, Wh, Wl,
                                                 bp, 1.f / BN);
            // v-gemm: elu-stats -> avg block (i+1) j0 slot (none after i=14)
            gemm_mfma<<<BN / 128, 256, 0, stream>>>(vA, msg, Wh, Wl, bp, vA, vA, vH,
                                                    (i < 14) ? slot(i + 1, 0) : nullptr,
                                                    N, 0, 1);

            // msg_f = Di @ v_out (gather vH); B-half stats -> slot(i,1)
            spmm_csr_kernel<<<RD / 32, 256, 0, stream>>>(ptrD, edgesD, (const __half2*)vH,
                                                         msg, RD, slot(i, 1));
            fold_kernel<<<128, 256, 0, stream>>>(slot(i, 1), g1, be1, Wl1, bl1, Wh, Wl,
                                                 bp, 1.f / BF);
            // f-gemm: elu-stats -> dir block (i+2) slot1, or final conv slot
            gemm_mfma<<<BF / 128, 256, 0, stream>>>(fA, msg, Wh, Wl, bp, nullptr, fA, fH,
                                                    (i < 14) ? slot(i + 2, 1) : Sfinal,
                                                    Fn, 0, 1);
        } else {
            for (int j = 0; j < 2; ++j) {
                const float* g = rn_gamma + (size_t)(i * 2 + j) * 256;
                const float* be = rn_beta + (size_t)(i * 2 + j) * 256;
                const float* Wlw = rn_W + (size_t)(i * 2 + j) * 256 * 128;
                const float* bl = rn_b + (size_t)(i * 2 + j) * 128;
                const float* src = (j == 0) ? vA : msg;
                float* dst = (j == 0) ? msg : vA;
                const float* resid = (j == 0) ? nullptr : vA;
                __half* shadow = (j == 0) ? nullptr : vH;
                // j=0 stats consumer: avg j=1 slot(i,1); j=1 consumer: dir(i+1) slot0
                float* Sout = (j == 0) ? slot(i, 1) : slot(i + 1, 0);

                float* avgacc = Aarena + 516 * aslot;
                float* masksum = avgacc + 512;
                aslot++;
                avgpool_kernel<<<dim3(N / 50, B), 128, 0, stream>>>(src, mask, avgacc,
                                                                    masksum, N, 50);
                finalize_avg<<<1, 128, 0, stream>>>(avgacc, masksum, avg, slot(i, j),
                                                    (float)N);
                fold_kernel<<<128, 256, 0, stream>>>(slot(i, j), g, be, Wlw, bl, Wh, Wl,
                                                     bp, 1.f / BN);
                gemm_mfma<<<BN / 128, 256, 0, stream>>>(src, avg, Wh, Wl, bp, resid, dst,
                                                        shadow, Sout, N, 1, 0);
            }
        }
    }

    fold_final<<<1, 128, 0, stream>>>(Sfinal, g2, be2, W2, b2, W2p, 1.f / BF);
    final_out_kernel<<<BF / 4, 256, 0, stream>>>(fA, W2p, out);
}

// Round 10
// 4723.507 us; speedup vs baseline: 1.4165x; 1.0485x over previous
//
#include <hip/hip_runtime.h>
#include <hip/hip_fp16.h>
#include <math.h>

// DirModelToFace on MI355X — round 10:
//  * spmm: restore wave parallelism lost in round 9 (144us vs round-7 115us; 8
//    sequential rows/wave starved latency hiding, Occ 61%). Now 1024-thread blocks
//    (16 waves) x 2 rows/wave: 4x the waves, same 1-atomic-per-address-per-block
//    Sout contention (3000 blocks for Di). Stats butterfly per row, ch=(r&3)*32+cp*2.
//  * everything else unchanged from round 9 (fused producer BN stats, dead layer 15
//    removed, bf16 hi/lo 3-MFMA GEMM with LDS-staged B, CSR build, packed edges).

#define EPS 1e-5f

typedef float floatx4 __attribute__((ext_vector_type(4)));
typedef short shortx8 __attribute__((ext_vector_type(8)));

__device__ __forceinline__ float eluf(float x) { return x > 0.f ? x : expm1f(x); }
__device__ __forceinline__ float4 elu4(float4 v) {
    v.x = eluf(v.x); v.y = eluf(v.y); v.z = eluf(v.z); v.w = eluf(v.w); return v;
}
__device__ __forceinline__ short f2bf(float x) {  // round-to-nearest-even bf16
    unsigned u = __builtin_bit_cast(unsigned, x);
    u = u + 0x7FFFu + ((u >> 16) & 1u);
    return (short)(u >> 16);
}
__device__ __forceinline__ float bf2f(short h) {
    unsigned u = ((unsigned)(unsigned short)h) << 16;
    return __builtin_bit_cast(float, u);
}

// v = inputs @ W1 + b1; fp16 shadow; fused elu-stats (A-half of dir0 slot0).
__global__ void conv1_kernel(const float* __restrict__ in, const float* __restrict__ W1,
                             const float* __restrict__ b1, float* __restrict__ v,
                             __half* __restrict__ vH, int N, float* __restrict__ Sout) {
    int t = threadIdx.x;
    int c = t & 127, half = t >> 7;
    int r0 = blockIdx.x * 64;
    float w0 = W1[c], w1 = W1[128 + c], w2 = W1[256 + c], bb = b1[c];
    float s1 = 0.f, s2 = 0.f;
    for (int k = 0; k < 32; ++k) {
        int r = r0 + half + 2 * k;
        float x0 = in[r * 3 + 0], x1 = in[r * 3 + 1], x2 = in[r * 3 + 2];
        float val = bb + x0 * w0 + x1 * w1 + x2 * w2;
        v[(size_t)r * 128 + c] = val;
        int b = r / N, vert = r - b * N;
        vH[(size_t)(4 * vert + (c >> 5)) * 128 + b * 32 + (c & 31)] = __float2half(val);
        float e = eluf(val);
        s1 += e; s2 += e * e;
    }
    atomicAdd(&Sout[c], s1);
    atomicAdd(&Sout[256 + c], s2);
}

// ---------------- CSR build ----------------

__global__ void hist_kernel(const int* __restrict__ rows, int* __restrict__ counts) {
    int e = blockIdx.x * 256 + threadIdx.x;
    atomicAdd(&counts[rows[e]], 1);
}

__global__ void partial_kernel(const int* __restrict__ counts, int* __restrict__ partials,
                               int R) {
    int t = threadIdx.x;
    int base = blockIdx.x * 1024 + t * 4;
    int s = 0;
#pragma unroll
    for (int j = 0; j < 4; ++j) { int i = base + j; if (i < R) s += counts[i]; }
    __shared__ int sh[256];
    sh[t] = s; __syncthreads();
    for (int st = 128; st > 0; st >>= 1) {
        if (t < st) sh[t] += sh[t + st];
        __syncthreads();
    }
    if (t == 0) partials[blockIdx.x] = sh[0];
}

__global__ void scanp_kernel(int* __restrict__ partials, int* __restrict__ rowptr,
                             int P, int R, int total) {
    __shared__ int sh[256];
    int t = threadIdx.x;
    int v = (t < P) ? partials[t] : 0;
    sh[t] = v; __syncthreads();
    for (int st = 1; st < 256; st <<= 1) {
        int tmp = (t >= st) ? sh[t - st] : 0;
        __syncthreads();
        sh[t] += tmp;
        __syncthreads();
    }
    if (t < P) partials[t] = sh[t] - v;
    if (t == 0) rowptr[R] = total;
}

__global__ void apply_kernel(int* __restrict__ counts, const int* __restrict__ partials,
                             int* __restrict__ rowptr, int R) {
    int t = threadIdx.x;
    int base = blockIdx.x * 1024 + t * 4;
    int c[4]; int s = 0;
#pragma unroll
    for (int j = 0; j < 4; ++j) { int i = base + j; c[j] = (i < R) ? counts[i] : 0; s += c[j]; }
    __shared__ int sh[256];
    sh[t] = s; __syncthreads();
    for (int st = 1; st < 256; st <<= 1) {
        int tmp = (t >= st) ? sh[t - st] : 0;
        __syncthreads();
        sh[t] += tmp;
        __syncthreads();
    }
    int off = partials[blockIdx.x] + sh[t] - s;
#pragma unroll
    for (int j = 0; j < 4; ++j) {
        int i = base + j;
        if (i < R) { rowptr[i] = off; counts[i] = off; }
        off += c[j];
    }
}

__global__ void scatter_kernel(const int* __restrict__ rows, const int* __restrict__ cols,
                               const float* __restrict__ vals, int* __restrict__ fill,
                               int2* __restrict__ edges) {
    int e = blockIdx.x * 256 + threadIdx.x;
    int p = atomicAdd(&fill[rows[e]], 1);
    edges[p] = make_int2(cols[e], __float_as_int(vals[e]));
}

// ---- CSR spmm: 16 waves/block, 2 rows/wave, 1 dword gather/edge, fused B stats ----
// lane l: batch = l>>4, channel pair cp = l&15. Flat msg channel = (r&3)*32 + cp*2.
__global__ __launch_bounds__(1024) void spmm_csr_kernel(
    const int* __restrict__ rowptr, const int2* __restrict__ edges,
    const __half2* __restrict__ xH, float* __restrict__ y, int R4,
    float* __restrict__ Sout) {
    int t = threadIdx.x;
    int waveId = blockIdx.x * 16 + (t >> 6);
    int lane = t & 63;
    int b = lane >> 4, cp = lane & 15;
    const __half2* xb = xH + b * 16 + cp;
    size_t rs = (size_t)R4 * 32;
    __shared__ float red[256];
    if (t < 256) red[t] = 0.f;
    __syncthreads();
#pragma unroll
    for (int rr = 0; rr < 2; ++rr) {
        int r = waveId * 2 + rr;
        int e0 = rowptr[r], e1 = rowptr[r + 1];
        float ax = 0.f, ay = 0.f;
        int e = e0;
        for (; e + 4 <= e1; e += 4) {
            int2 E0 = edges[e], E1 = edges[e + 1], E2 = edges[e + 2], E3 = edges[e + 3];
            __half2 g0 = xb[(size_t)E0.x * 64];
            __half2 g1 = xb[(size_t)E1.x * 64];
            __half2 g2 = xb[(size_t)E2.x * 64];
            __half2 g3 = xb[(size_t)E3.x * 64];
            float v0 = __int_as_float(E0.y), v1 = __int_as_float(E1.y);
            float v2 = __int_as_float(E2.y), v3 = __int_as_float(E3.y);
            float2 f0 = __half22float2(g0), f1 = __half22float2(g1);
            float2 f2 = __half22float2(g2), f3 = __half22float2(g3);
            ax += v0 * f0.x; ay += v0 * f0.y;
            ax += v1 * f1.x; ay += v1 * f1.y;
            ax += v2 * f2.x; ay += v2 * f2.y;
            ax += v3 * f3.x; ay += v3 * f3.y;
        }
        for (; e < e1; ++e) {
            int2 E = edges[e];
            __half2 g = xb[(size_t)E.x * 64];
            float v = __int_as_float(E.y);
            float2 f = __half22float2(g);
            ax += v * f.x; ay += v * f.y;
        }
        *(float2*)&y[(size_t)b * rs + (size_t)r * 32 + cp * 2] = make_float2(ax, ay);
        // fused B-half stats for this row
        float ea = eluf(ax), eb = eluf(ay);
        float s1a = ea, s2a = ea * ea, s1b = eb, s2b = eb * eb;
        s1a += __shfl_xor(s1a, 16); s1a += __shfl_xor(s1a, 32);
        s2a += __shfl_xor(s2a, 16); s2a += __shfl_xor(s2a, 32);
        s1b += __shfl_xor(s1b, 16); s1b += __shfl_xor(s1b, 32);
        s2b += __shfl_xor(s2b, 16); s2b += __shfl_xor(s2b, 32);
        if (lane < 16) {
            int ch = (r & 3) * 32 + cp * 2;
            atomicAdd(&red[ch], s1a);
            atomicAdd(&red[ch + 1], s1b);
            atomicAdd(&red[128 + ch], s2a);
            atomicAdd(&red[128 + ch + 1], s2b);
        }
    }
    __syncthreads();
    if (t < 128) atomicAdd(&Sout[128 + t], red[t]);
    else if (t < 256) atomicAdd(&Sout[384 + (t - 128)], red[t]);
}

// Fold BN into weights; emit bf16 hi/lo split in [col][k] layout for MFMA B-frags.
__global__ void fold_kernel(const float* __restrict__ S, const float* __restrict__ gamma,
                            const float* __restrict__ beta, const float* __restrict__ W,
                            const float* __restrict__ bvec, short* __restrict__ Wh,
                            short* __restrict__ Wl, float* __restrict__ bp, float invR) {
    __shared__ float red[256];
    int o = blockIdx.x, k = threadIdx.x;
    float mean = S[k] * invR;
    float var = S[256 + k] * invR - mean * mean;
    float s = gamma[k] / sqrtf(var + EPS);
    float w = W[(size_t)k * 128 + o];
    float wp = s * w;
    short h = f2bf(wp);
    Wh[(size_t)o * 256 + k] = h;
    Wl[(size_t)o * 256 + k] = f2bf(wp - bf2f(h));
    red[k] = (beta[k] - mean * s) * w;
    __syncthreads();
    for (int st = 128; st > 0; st >>= 1) {
        if (k < st) red[k] += red[k + st];
        __syncthreads();
    }
    if (k == 0) bp[o] = bvec[o] + red[0];
}

// MFMA GEMM (bf16 hi/lo split, fp32 acc), LDS-staged B, fused elu-stats epilogue.
__global__ __launch_bounds__(256) void gemm_mfma(
    const float* __restrict__ A, const float* __restrict__ Bs,
    const short* __restrict__ Wh, const short* __restrict__ Wl,
    const float* __restrict__ bp, const float* __restrict__ resid,
    float* __restrict__ out, __half* __restrict__ shadow,
    float* __restrict__ Sout, int rowsPerBatch, int modeB, int eluB) {
    __shared__ short Bsh[128 * 40];
    __shared__ short Bsl[128 * 40];
    const int t = threadIdx.x;
    const int lane = t & 63;
    const int wave = t >> 6;
    const int rowBase = blockIdx.x * 128 + wave * 32;
    const int m = lane & 15;
    const int kq = lane >> 4;
    floatx4 acc[2][8];
#pragma unroll
    for (int i = 0; i < 2; ++i)
#pragma unroll
        for (int j = 0; j < 8; ++j) acc[i][j] = {0.f, 0.f, 0.f, 0.f};

    for (int kb = 0; kb < 8; ++kb) {
        const int k0 = kb * 32 + kq * 8;
        __syncthreads();
#pragma unroll
        for (int i = 0; i < 2; ++i) {
            int idx = t + 256 * i;
            int col = idx >> 2, q = idx & 3;
            shortx8 h = *(const shortx8*)&Wh[(size_t)col * 256 + kb * 32 + q * 8];
            shortx8 l = *(const shortx8*)&Wl[(size_t)col * 256 + kb * 32 + q * 8];
            *(shortx8*)&Bsh[col * 40 + q * 8] = h;
            *(shortx8*)&Bsl[col * 40 + q * 8] = l;
        }
        shortx8 ah[2], al[2];
#pragma unroll
        for (int rg = 0; rg < 2; ++rg) {
            int row = rowBase + rg * 16 + m;
            float4 p, q;
            if (kb < 4) {
                p = elu4(*(const float4*)&A[(size_t)row * 128 + k0]);
                q = elu4(*(const float4*)&A[(size_t)row * 128 + k0 + 4]);
            } else {
                int kk = k0 - 128;
                if (modeB == 0) {
                    p = *(const float4*)&Bs[(size_t)row * 128 + kk];
                    q = *(const float4*)&Bs[(size_t)row * 128 + kk + 4];
                    if (eluB) { p = elu4(p); q = elu4(q); }
                } else {
                    int b = row / rowsPerBatch;
                    p = *(const float4*)&Bs[b * 128 + kk];
                    q = *(const float4*)&Bs[b * 128 + kk + 4];
                }
            }
            float x[8] = {p.x, p.y, p.z, p.w, q.x, q.y, q.z, q.w};
#pragma unroll
            for (int j = 0; j < 8; ++j) {
                short h = f2bf(x[j]);
                ah[rg][j] = h;
                al[rg][j] = f2bf(x[j] - bf2f(h));
            }
        }
        __syncthreads();
#pragma unroll
        for (int ct = 0; ct < 8; ++ct) {
            int co = (ct * 16 + m) * 40 + kq * 8;
            shortx8 bh = *(const shortx8*)&Bsh[co];
            shortx8 bl = *(const shortx8*)&Bsl[co];
#pragma unroll
            for (int rg = 0; rg < 2; ++rg) {
                acc[rg][ct] = __builtin_amdgcn_mfma_f32_16x16x32_bf16(ah[rg], bh, acc[rg][ct], 0, 0, 0);
                acc[rg][ct] = __builtin_amdgcn_mfma_f32_16x16x32_bf16(ah[rg], bl, acc[rg][ct], 0, 0, 0);
                acc[rg][ct] = __builtin_amdgcn_mfma_f32_16x16x32_bf16(al[rg], bh, acc[rg][ct], 0, 0, 0);
            }
        }
    }
    // epilogue: C/D layout col=lane&15, row=(lane>>4)*4+reg  [verified m89/m91]
    float cs1[8], cs2[8];
#pragma unroll
    for (int ct = 0; ct < 8; ++ct) { cs1[ct] = 0.f; cs2[ct] = 0.f; }
#pragma unroll
    for (int ct = 0; ct < 8; ++ct) {
        int col = ct * 16 + m;
        float bb = bp[col];
#pragma unroll
        for (int rg = 0; rg < 2; ++rg) {
#pragma unroll
            for (int r = 0; r < 4; ++r) {
                int row = rowBase + rg * 16 + kq * 4 + r;
                size_t o = (size_t)row * 128 + col;
                float v = acc[rg][ct][r] + bb;
                if (resid) v += resid[o];
                out[o] = v;
                if (shadow) {
                    int b = row / rowsPerBatch, vert = row - b * rowsPerBatch;
                    shadow[(size_t)(4 * vert + (col >> 5)) * 128 + b * 32 + (col & 31)] =
                        __float2half(v);
                }
                float e = eluf(v);
                cs1[ct] += e; cs2[ct] += e * e;
            }
        }
    }
    if (Sout) {  // fused elu-stats for the consuming layer's BN (A-half)
        __syncthreads();           // all waves done with Bsh
        float* red = (float*)Bsh;  // 256 floats
        red[t] = 0.f;
        __syncthreads();
#pragma unroll
        for (int ct = 0; ct < 8; ++ct) {
            cs1[ct] += __shfl_xor(cs1[ct], 16); cs1[ct] += __shfl_xor(cs1[ct], 32);
            cs2[ct] += __shfl_xor(cs2[ct], 16); cs2[ct] += __shfl_xor(cs2[ct], 32);
        }
        if (kq == 0) {
#pragma unroll
            for (int ct = 0; ct < 8; ++ct) {
                atomicAdd(&red[ct * 16 + m], cs1[ct]);
                atomicAdd(&red[128 + ct * 16 + m], cs2[ct]);
            }
        }
        __syncthreads();
        if (t < 128) atomicAdd(&Sout[t], red[t]);
        else atomicAdd(&Sout[256 + (t - 128)], red[t]);
    }
}

// masked mean of elu(X): partial sums via atomics into pre-zeroed arena slot
__global__ void avgpool_kernel(const float* __restrict__ X, const float* __restrict__ mask,
                               float* __restrict__ avgacc, float* __restrict__ masksum,
                               int N, int rpb) {
    int b = blockIdx.y, t = threadIdx.x;
    int n0 = blockIdx.x * rpb;
    int n1 = min(n0 + rpb, N);
    float acc = 0.f, mac = 0.f;
    for (int n = n0; n < n1; ++n) {
        float m = mask[(size_t)b * N + n];
        float v = eluf(X[((size_t)b * N + n) * 128 + t]);
        acc += m * v;
        mac += m;
    }
    atomicAdd(&avgacc[b * 128 + t], acc);
    if (t == 0) atomicAdd(&masksum[b], mac);
}

__global__ void finalize_avg(const float* __restrict__ avgacc, const float* __restrict__ masksum,
                             float* __restrict__ avg, float* __restrict__ S, float fN) {
    int c = threadIdx.x;
    float s1 = 0.f, s2 = 0.f;
    for (int b = 0; b < 4; ++b) {
        float a = avgacc[b * 128 + c] / masksum[b];
        avg[b * 128 + c] = a;
        s1 += a; s2 += a * a;
    }
    S[128 + c] = s1 * fN;
    S[256 + 128 + c] = s2 * fN;
}

__global__ void fold_final(const float* __restrict__ S, const float* __restrict__ g2,
                           const float* __restrict__ be2, const float* __restrict__ W2,
                           const float* __restrict__ b2, float* __restrict__ W2p, float invR) {
    __shared__ float red[128];
    int c = threadIdx.x;
    float mean = S[c] * invR;
    float var = S[256 + c] * invR - mean * mean;
    float s = g2[c] / sqrtf(var + EPS);
    float w = W2[c];
    W2p[c] = s * w;
    red[c] = (be2[c] - mean * s) * w;
    __syncthreads();
    for (int st = 64; st > 0; st >>= 1) {
        if (c < st) red[c] += red[c + st];
        __syncthreads();
    }
    if (c == 0) W2p[128] = b2[0] + red[0];
}

__global__ void final_out_kernel(const float* __restrict__ f, const float* __restrict__ W2p,
                                 float* __restrict__ out) {
    int t = threadIdx.x;
    int w = t >> 6, lane = t & 63;
    int row = blockIdx.x * 4 + w;
    float a = eluf(f[(size_t)row * 128 + lane]) * W2p[lane] +
              eluf(f[(size_t)row * 128 + 64 + lane]) * W2p[64 + lane];
    for (int off = 32; off > 0; off >>= 1) a += __shfl_down(a, off);
    if (lane == 0) out[row] = a + W2p[128];
}

extern "C" void kernel_launch(void* const* d_in, const int* in_sizes, int n_in,
                              void* d_out, int out_size, void* d_ws, size_t ws_size,
                              hipStream_t stream) {
    const float* inputs = (const float*)d_in[0];
    const float* mask = (const float*)d_in[1];
    const int* Di_rows = (const int*)d_in[2];
    const int* Di_cols = (const int*)d_in[3];
    const float* Di_vals = (const float*)d_in[4];
    const int* DiA_rows = (const int*)d_in[5];
    const int* DiA_cols = (const int*)d_in[6];
    const float* DiA_vals = (const float*)d_in[7];
    const float* W1 = (const float*)d_in[8];
    const float* b1 = (const float*)d_in[9];
    const float* rn_gamma = (const float*)d_in[10];
    const float* rn_beta = (const float*)d_in[11];
    const float* rn_W = (const float*)d_in[12];
    const float* rn_b = (const float*)d_in[13];
    const float* g2 = (const float*)d_in[14];
    const float* be2 = (const float*)d_in[15];
    const float* W2 = (const float*)d_in[16];
    const float* b2 = (const float*)d_in[17];
    float* out = (float*)d_out;

    const int B = 4;
    const int BN = in_sizes[1];      // 48000
    const int N = BN / B;            // 12000
    const int BF = out_size;         // 96000
    const int Fn = BF / B;           // 24000
    const int nnz = in_sizes[2];     // 1,152,000
    const int RA = 4 * N;            // 48000
    const int RD = 4 * Fn;           // 96000

    float* ws = (float*)d_ws;
    size_t off = 0;
    float* vA = ws + off;  off += (size_t)BN * 128;
    float* fA = ws + off;  off += (size_t)BF * 128;
    float* msg = ws + off; off += (size_t)BF * 128;
    __half* vH = (__half*)(ws + off); off += (size_t)RA * 128 / 2;  // [r4][b][32] fp16
    __half* fH = (__half*)(ws + off); off += (size_t)RD * 128 / 2;
    int* ptrA    = (int*)(ws + off);  off += (size_t)RA + 4;
    int2* edgesA = (int2*)(ws + off); off += (size_t)nnz * 2;
    int* ptrD    = (int*)(ws + off);  off += (size_t)RD + 4;
    int2* edgesD = (int2*)(ws + off); off += (size_t)nnz * 2;
    int* tmpfill = (int*)(ws + off);  off += (size_t)RD;
    int* partials = (int*)(ws + off); off += 256;
    float* Sarena = ws + off; off += 33 * 512;   // pre-zeroed stats slots (2i+j map)
    float* Aarena = ws + off; off += 16 * 516;   // pre-zeroed avgpool slots
    float* avg = ws + off;    off += 512;
    short* Wh = (short*)(ws + off); off += 128 * 256 / 2;
    short* Wl = (short*)(ws + off); off += 128 * 256 / 2;
    float* bp = ws + off;  off += 128;
    float* W2p = ws + off; off += 132;

    const int eBlocks = nnz / 256;
    const int PA = (RA + 1023) / 1024;
    const int PD = (RD + 1023) / 1024;

    hipMemsetAsync(Sarena, 0, (33 * 512 + 16 * 516) * 4, stream);
    hipMemsetAsync(fA, 0, (size_t)BF * 128 * 4, stream);
    hipMemsetAsync(fH, 0, (size_t)RD * 128 * 2, stream);

    // ---- build CSR for DiA ----
    hipMemsetAsync(tmpfill, 0, (size_t)RA * 4, stream);
    hist_kernel<<<eBlocks, 256, 0, stream>>>(DiA_rows, tmpfill);
    partial_kernel<<<PA, 256, 0, stream>>>(tmpfill, partials, RA);
    scanp_kernel<<<1, 256, 0, stream>>>(partials, ptrA, PA, RA, nnz);
    apply_kernel<<<PA, 256, 0, stream>>>(tmpfill, partials, ptrA, RA);
    scatter_kernel<<<eBlocks, 256, 0, stream>>>(DiA_rows, DiA_cols, DiA_vals, tmpfill, edgesA);
    // ---- build CSR for Di ----
    hipMemsetAsync(tmpfill, 0, (size_t)RD * 4, stream);
    hist_kernel<<<eBlocks, 256, 0, stream>>>(Di_rows, tmpfill);
    partial_kernel<<<PD, 256, 0, stream>>>(tmpfill, partials, RD);
    scanp_kernel<<<1, 256, 0, stream>>>(partials, ptrD, PD, RD, nnz);
    apply_kernel<<<PD, 256, 0, stream>>>(tmpfill, partials, ptrD, RD);
    scatter_kernel<<<eBlocks, 256, 0, stream>>>(Di_rows, Di_cols, Di_vals, tmpfill, edgesD);

    // S slot map: conv layer (i,j) -> Sarena + 512*(2i+j); final conv -> slot 32
    auto slot = [&](int i, int j) { return Sarena + 512 * (2 * i + j); };
    float* Sfinal = Sarena + 512 * 32;

    conv1_kernel<<<BN / 64, 256, 0, stream>>>(inputs, W1, b1, vA, vH, N, slot(0, 0));

    int aslot = 0;
    for (int i = 0; i < 15; ++i) {   // layer 15 (avg) is dead: output depends only on f
        if ((i & 1) == 0) {
            const float* g0 = rn_gamma + (size_t)(i * 2 + 0) * 256;
            const float* be0 = rn_beta + (size_t)(i * 2 + 0) * 256;
            const float* Wl0 = rn_W + (size_t)(i * 2 + 0) * 256 * 128;
            const float* bl0 = rn_b + (size_t)(i * 2 + 0) * 128;
            const float* g1 = rn_gamma + (size_t)(i * 2 + 1) * 256;
            const float* be1 = rn_beta + (size_t)(i * 2 + 1) * 256;
            const float* Wl1 = rn_W + (size_t)(i * 2 + 1) * 256 * 128;
            const float* bl1 = rn_b + (size_t)(i * 2 + 1) * 128;

            // msg_v = DiA @ f (gather fH); B-half stats -> slot(i,0)
            spmm_csr_kernel<<<RA / 32, 1024, 0, stream>>>(ptrA, edgesA, (const __half2*)fH,
                                                          msg, RA, slot(i, 0));
            fold_kernel<<<128, 256, 0, stream>>>(slot(i, 0), g0, be0, Wl0, bl0, Wh, Wl,
                                                 bp, 1.f / BN);
            // v-gemm: elu-stats -> avg block (i+1) j0 slot (none after i=14)
            gemm_mfma<<<BN / 128, 256, 0, stream>>>(vA, msg, Wh, Wl, bp, vA, vA, vH,
                                                    (i < 14) ? slot(i + 1, 0) : nullptr,
                                                    N, 0, 1);

            // msg_f = Di @ v_out (gather vH); B-half stats -> slot(i,1)
            spmm_csr_kernel<<<RD / 32, 1024, 0, stream>>>(ptrD, edgesD, (const __half2*)vH,
                                                          msg, RD, slot(i, 1));
            fold_kernel<<<128, 256, 0, stream>>>(slot(i, 1), g1, be1, Wl1, bl1, Wh, Wl,
                                                 bp, 1.f / BF);
            // f-gemm: elu-stats -> dir block (i+2) slot1, or final conv slot
            gemm_mfma<<<BF / 128, 256, 0, stream>>>(fA, msg, Wh, Wl, bp, nullptr, fA, fH,
                                                    (i < 14) ? slot(i + 2, 1) : Sfinal,
                                                    Fn, 0, 1);
        } else {
            for (int j = 0; j < 2; ++j) {
                const float* g = rn_gamma + (size_t)(i * 2 + j) * 256;
                const float* be = rn_beta + (size_t)(i * 2 + j) * 256;
                const float* Wlw = rn_W + (size_t)(i * 2 + j) * 256 * 128;
                const float* bl = rn_b + (size_t)(i * 2 + j) * 128;
                const float* src = (j == 0) ? vA : msg;
                float* dst = (j == 0) ? msg : vA;
                const float* resid = (j == 0) ? nullptr : vA;
                __half* shadow = (j == 0) ? nullptr : vH;
                // j=0 stats consumer: avg j=1 slot(i,1); j=1 consumer: dir(i+1) slot0
                float* Sout = (j == 0) ? slot(i, 1) : slot(i + 1, 0);

                float* avgacc = Aarena + 516 * aslot;
                float* masksum = avgacc + 512;
                aslot++;
                avgpool_kernel<<<dim3(N / 50, B), 128, 0, stream>>>(src, mask, avgacc,
                                                                    masksum, N, 50);
                finalize_avg<<<1, 128, 0, stream>>>(avgacc, masksum, avg, slot(i, j),
                                                    (float)N);
                fold_kernel<<<128, 256, 0, stream>>>(slot(i, j), g, be, Wlw, bl, Wh, Wl,
                                                     bp, 1.f / BN);
                gemm_mfma<<<BN / 128, 256, 0, stream>>>(src, avg, Wh, Wl, bp, resid, dst,
                                                        shadow, Sout, N, 1, 0);
            }
        }
    }

    fold_final<<<1, 128, 0, stream>>>(Sfinal, g2, be2, W2, b2, W2p, 1.f / BF);
    final_out_kernel<<<BF / 4, 256, 0, stream>>>(fA, W2p, out);
}

// Round 11
// 4195.280 us; speedup vs baseline: 1.5949x; 1.1259x over previous
//
#include <hip/hip_runtime.h>
#include <hip/hip_fp16.h>
#include <math.h>

// DirModelToFace on MI355X — round 11:
//  * gemm A-split: RNE (8 ops/elt) -> truncation split (4 ops/elt; rem = x-bf2f(hi)
//    exact in fp32, lo=trunc(rem), total err <= 2^-16). Gemm was VALU-bound (r6: 31%).
//  * layer 0: f==0 -> msg_v==0 exactly: skip first DiA spmm + fH memset; layer-0
//    v-gemm modeB=2 (zero B-half, K-loop kb<4 only). Stats slots stay 0 = exact.
//  * avgpool fused into producer gemm epilogues (masked elu-sums per (b,col) via
//    butterfly + LDS; masksum is feature-independent -> one tiny kernel at start).
//    Deletes 14 avgpool dispatches.
//  * rest as round 10: fused producer BN stats, dead layer 15 removed, 16-wave spmm,
//    bf16 hi/lo 3-MFMA GEMM with LDS-staged B, CSR build with packed edges.

#define EPS 1e-5f

typedef float floatx4 __attribute__((ext_vector_type(4)));
typedef short shortx8 __attribute__((ext_vector_type(8)));

__device__ __forceinline__ float eluf(float x) { return x > 0.f ? x : expm1f(x); }
__device__ __forceinline__ float4 elu4(float4 v) {
    v.x = eluf(v.x); v.y = eluf(v.y); v.z = eluf(v.z); v.w = eluf(v.w); return v;
}
__device__ __forceinline__ short f2bf(float x) {  // round-to-nearest-even bf16
    unsigned u = __builtin_bit_cast(unsigned, x);
    u = u + 0x7FFFu + ((u >> 16) & 1u);
    return (short)(u >> 16);
}
__device__ __forceinline__ float bf2f(short h) {
    unsigned u = ((unsigned)(unsigned short)h) << 16;
    return __builtin_bit_cast(float, u);
}
// truncation hi/lo split: hi=trunc(x), rem exact, lo=trunc(rem); err <= 2^-16|x|
__device__ __forceinline__ void split2(float x, short& hi, short& lo) {
    unsigned u = __builtin_bit_cast(unsigned, x);
    hi = (short)(u >> 16);
    float r = x - bf2f(hi);
    lo = (short)(__builtin_bit_cast(unsigned, r) >> 16);
}

// v = inputs @ W1 + b1; fp16 shadow; fused elu-stats (A-half of dir0 slot0).
__global__ void conv1_kernel(const float* __restrict__ in, const float* __restrict__ W1,
                             const float* __restrict__ b1, float* __restrict__ v,
                             __half* __restrict__ vH, int N, float* __restrict__ Sout) {
    int t = threadIdx.x;
    int c = t & 127, half = t >> 7;
    int r0 = blockIdx.x * 64;
    float w0 = W1[c], w1 = W1[128 + c], w2 = W1[256 + c], bb = b1[c];
    float s1 = 0.f, s2 = 0.f;
    for (int k = 0; k < 32; ++k) {
        int r = r0 + half + 2 * k;
        float x0 = in[r * 3 + 0], x1 = in[r * 3 + 1], x2 = in[r * 3 + 2];
        float val = bb + x0 * w0 + x1 * w1 + x2 * w2;
        v[(size_t)r * 128 + c] = val;
        int b = r / N, vert = r - b * N;
        vH[(size_t)(4 * vert + (c >> 5)) * 128 + b * 32 + (c & 31)] = __float2half(val);
        float e = eluf(val);
        s1 += e; s2 += e * e;
    }
    atomicAdd(&Sout[c], s1);
    atomicAdd(&Sout[256 + c], s2);
}

// masksum[b] = sum_n mask[b][n]  (feature-independent; once per launch)
__global__ void masksum_kernel(const float* __restrict__ mask, float* __restrict__ msum,
                               int N) {
    int b = blockIdx.x, t = threadIdx.x;
    float s = 0.f;
    for (int n = t; n < N; n += 256) s += mask[(size_t)b * N + n];
    for (int o = 32; o > 0; o >>= 1) s += __shfl_down(s, o);
    __shared__ float sh[4];
    if ((t & 63) == 0) sh[t >> 6] = s;
    __syncthreads();
    if (t == 0) msum[b] = sh[0] + sh[1] + sh[2] + sh[3];
}

// ---------------- CSR build ----------------

__global__ void hist_kernel(const int* __restrict__ rows, int* __restrict__ counts) {
    int e = blockIdx.x * 256 + threadIdx.x;
    atomicAdd(&counts[rows[e]], 1);
}

__global__ void partial_kernel(const int* __restrict__ counts, int* __restrict__ partials,
                               int R) {
    int t = threadIdx.x;
    int base = blockIdx.x * 1024 + t * 4;
    int s = 0;
#pragma unroll
    for (int j = 0; j < 4; ++j) { int i = base + j; if (i < R) s += counts[i]; }
    __shared__ int sh[256];
    sh[t] = s; __syncthreads();
    for (int st = 128; st > 0; st >>= 1) {
        if (t < st) sh[t] += sh[t + st];
        __syncthreads();
    }
    if (t == 0) partials[blockIdx.x] = sh[0];
}

__global__ void scanp_kernel(int* __restrict__ partials, int* __restrict__ rowptr,
                             int P, int R, int total) {
    __shared__ int sh[256];
    int t = threadIdx.x;
    int v = (t < P) ? partials[t] : 0;
    sh[t] = v; __syncthreads();
    for (int st = 1; st < 256; st <<= 1) {
        int tmp = (t >= st) ? sh[t - st] : 0;
        __syncthreads();
        sh[t] += tmp;
        __syncthreads();
    }
    if (t < P) partials[t] = sh[t] - v;
    if (t == 0) rowptr[R] = total;
}

__global__ void apply_kernel(int* __restrict__ counts, const int* __restrict__ partials,
                             int* __restrict__ rowptr, int R) {
    int t = threadIdx.x;
    int base = blockIdx.x * 1024 + t * 4;
    int c[4]; int s = 0;
#pragma unroll
    for (int j = 0; j < 4; ++j) { int i = base + j; c[j] = (i < R) ? counts[i] : 0; s += c[j]; }
    __shared__ int sh[256];
    sh[t] = s; __syncthreads();
    for (int st = 1; st < 256; st <<= 1) {
        int tmp = (t >= st) ? sh[t - st] : 0;
        __syncthreads();
        sh[t] += tmp;
        __syncthreads();
    }
    int off = partials[blockIdx.x] + sh[t] - s;
#pragma unroll
    for (int j = 0; j < 4; ++j) {
        int i = base + j;
        if (i < R) { rowptr[i] = off; counts[i] = off; }
        off += c[j];
    }
}

__global__ void scatter_kernel(const int* __restrict__ rows, const int* __restrict__ cols,
                               const float* __restrict__ vals, int* __restrict__ fill,
                               int2* __restrict__ edges) {
    int e = blockIdx.x * 256 + threadIdx.x;
    int p = atomicAdd(&fill[rows[e]], 1);
    edges[p] = make_int2(cols[e], __float_as_int(vals[e]));
}

// ---- CSR spmm: 16 waves/block, 2 rows/wave, 1 dword gather/edge, fused B stats ----
__global__ __launch_bounds__(1024) void spmm_csr_kernel(
    const int* __restrict__ rowptr, const int2* __restrict__ edges,
    const __half2* __restrict__ xH, float* __restrict__ y, int R4,
    float* __restrict__ Sout) {
    int t = threadIdx.x;
    int waveId = blockIdx.x * 16 + (t >> 6);
    int lane = t & 63;
    int b = lane >> 4, cp = lane & 15;
    const __half2* xb = xH + b * 16 + cp;
    size_t rs = (size_t)R4 * 32;
    __shared__ float red[256];
    if (t < 256) red[t] = 0.f;
    __syncthreads();
#pragma unroll
    for (int rr = 0; rr < 2; ++rr) {
        int r = waveId * 2 + rr;
        int e0 = rowptr[r], e1 = rowptr[r + 1];
        float ax = 0.f, ay = 0.f;
        int e = e0;
        for (; e + 4 <= e1; e += 4) {
            int2 E0 = edges[e], E1 = edges[e + 1], E2 = edges[e + 2], E3 = edges[e + 3];
            __half2 g0 = xb[(size_t)E0.x * 64];
            __half2 g1 = xb[(size_t)E1.x * 64];
            __half2 g2 = xb[(size_t)E2.x * 64];
            __half2 g3 = xb[(size_t)E3.x * 64];
            float v0 = __int_as_float(E0.y), v1 = __int_as_float(E1.y);
            float v2 = __int_as_float(E2.y), v3 = __int_as_float(E3.y);
            float2 f0 = __half22float2(g0), f1 = __half22float2(g1);
            float2 f2 = __half22float2(g2), f3 = __half22float2(g3);
            ax += v0 * f0.x; ay += v0 * f0.y;
            ax += v1 * f1.x; ay += v1 * f1.y;
            ax += v2 * f2.x; ay += v2 * f2.y;
            ax += v3 * f3.x; ay += v3 * f3.y;
        }
        for (; e < e1; ++e) {
            int2 E = edges[e];
            __half2 g = xb[(size_t)E.x * 64];
            float v = __int_as_float(E.y);
            float2 f = __half22float2(g);
            ax += v * f.x; ay += v * f.y;
        }
        *(float2*)&y[(size_t)b * rs + (size_t)r * 32 + cp * 2] = make_float2(ax, ay);
        float ea = eluf(ax), eb = eluf(ay);
        float s1a = ea, s2a = ea * ea, s1b = eb, s2b = eb * eb;
        s1a += __shfl_xor(s1a, 16); s1a += __shfl_xor(s1a, 32);
        s2a += __shfl_xor(s2a, 16); s2a += __shfl_xor(s2a, 32);
        s1b += __shfl_xor(s1b, 16); s1b += __shfl_xor(s1b, 32);
        s2b += __shfl_xor(s2b, 16); s2b += __shfl_xor(s2b, 32);
        if (lane < 16) {
            int ch = (r & 3) * 32 + cp * 2;
            atomicAdd(&red[ch], s1a);
            atomicAdd(&red[ch + 1], s1b);
            atomicAdd(&red[128 + ch], s2a);
            atomicAdd(&red[128 + ch + 1], s2b);
        }
    }
    __syncthreads();
    if (t < 128) atomicAdd(&Sout[128 + t], red[t]);
    else if (t < 256) atomicAdd(&Sout[384 + (t - 128)], red[t]);
}

// Fold BN into weights; emit bf16 hi/lo split in [col][k] layout for MFMA B-frags.
__global__ void fold_kernel(const float* __restrict__ S, const float* __restrict__ gamma,
                            const float* __restrict__ beta, const float* __restrict__ W,
                            const float* __restrict__ bvec, short* __restrict__ Wh,
                            short* __restrict__ Wl, float* __restrict__ bp, float invR) {
    __shared__ float red[256];
    int o = blockIdx.x, k = threadIdx.x;
    float mean = S[k] * invR;
    float var = S[256 + k] * invR - mean * mean;
    float s = gamma[k] / sqrtf(var + EPS);
    float w = W[(size_t)k * 128 + o];
    float wp = s * w;
    short h = f2bf(wp);
    Wh[(size_t)o * 256 + k] = h;
    Wl[(size_t)o * 256 + k] = f2bf(wp - bf2f(h));
    red[k] = (beta[k] - mean * s) * w;
    __syncthreads();
    for (int st = 128; st > 0; st >>= 1) {
        if (k < st) red[k] += red[k + st];
        __syncthreads();
    }
    if (k == 0) bp[o] = bvec[o] + red[0];
}

// MFMA GEMM (bf16 hi/lo split, fp32 acc), LDS-staged B, fused elu-stats + avg epilogue.
// modeB: 0 = per-row B, 1 = broadcast avg, 2 = B is identically zero (skip kb>=4).
__global__ __launch_bounds__(256) void gemm_mfma(
    const float* __restrict__ A, const float* __restrict__ Bs,
    const short* __restrict__ Wh, const short* __restrict__ Wl,
    const float* __restrict__ bp, const float* __restrict__ resid,
    float* __restrict__ out, __half* __restrict__ shadow,
    float* __restrict__ Sout, const float* __restrict__ mask,
    float* __restrict__ avgout, int rowsPerBatch, int modeB, int eluB) {
    __shared__ short Bsh[128 * 40];
    __shared__ short Bsl[128 * 40];
    const int t = threadIdx.x;
    const int lane = t & 63;
    const int wave = t >> 6;
    const int rowBase = blockIdx.x * 128 + wave * 32;
    const int m = lane & 15;
    const int kq = lane >> 4;
    floatx4 acc[2][8];
#pragma unroll
    for (int i = 0; i < 2; ++i)
#pragma unroll
        for (int j = 0; j < 8; ++j) acc[i][j] = {0.f, 0.f, 0.f, 0.f};

    const int kbEnd = (modeB == 2) ? 4 : 8;
    for (int kb = 0; kb < kbEnd; ++kb) {
        const int k0 = kb * 32 + kq * 8;
        __syncthreads();
#pragma unroll
        for (int i = 0; i < 2; ++i) {
            int idx = t + 256 * i;
            int col = idx >> 2, q = idx & 3;
            shortx8 h = *(const shortx8*)&Wh[(size_t)col * 256 + kb * 32 + q * 8];
            shortx8 l = *(const shortx8*)&Wl[(size_t)col * 256 + kb * 32 + q * 8];
            *(shortx8*)&Bsh[col * 40 + q * 8] = h;
            *(shortx8*)&Bsl[col * 40 + q * 8] = l;
        }
        shortx8 ah[2], al[2];
#pragma unroll
        for (int rg = 0; rg < 2; ++rg) {
            int row = rowBase + rg * 16 + m;
            float4 p, q;
            if (kb < 4) {
                p = elu4(*(const float4*)&A[(size_t)row * 128 + k0]);
                q = elu4(*(const float4*)&A[(size_t)row * 128 + k0 + 4]);
            } else {
                int kk = k0 - 128;
                if (modeB == 0) {
                    p = *(const float4*)&Bs[(size_t)row * 128 + kk];
                    q = *(const float4*)&Bs[(size_t)row * 128 + kk + 4];
                    if (eluB) { p = elu4(p); q = elu4(q); }
                } else {
                    int b = row / rowsPerBatch;
                    p = *(const float4*)&Bs[b * 128 + kk];
                    q = *(const float4*)&Bs[b * 128 + kk + 4];
                }
            }
            float x[8] = {p.x, p.y, p.z, p.w, q.x, q.y, q.z, q.w};
#pragma unroll
            for (int j = 0; j < 8; ++j) {
                short h, l;
                split2(x[j], h, l);
                ah[rg][j] = h;
                al[rg][j] = l;
            }
        }
        __syncthreads();
#pragma unroll
        for (int ct = 0; ct < 8; ++ct) {
            int co = (ct * 16 + m) * 40 + kq * 8;
            shortx8 bh = *(const shortx8*)&Bsh[co];
            shortx8 bl = *(const shortx8*)&Bsl[co];
#pragma unroll
            for (int rg = 0; rg < 2; ++rg) {
                acc[rg][ct] = __builtin_amdgcn_mfma_f32_16x16x32_bf16(ah[rg], bh, acc[rg][ct], 0, 0, 0);
                acc[rg][ct] = __builtin_amdgcn_mfma_f32_16x16x32_bf16(ah[rg], bl, acc[rg][ct], 0, 0, 0);
                acc[rg][ct] = __builtin_amdgcn_mfma_f32_16x16x32_bf16(al[rg], bh, acc[rg][ct], 0, 0, 0);
            }
        }
    }
    // epilogue: C/D layout col=lane&15, row=(lane>>4)*4+reg  [verified m89/m91]
    const int bBlk = (blockIdx.x * 128) / rowsPerBatch;  // block spans <=2 batches
    float mk8[8]; int ib8[8];
    if (avgout) {
#pragma unroll
        for (int rg = 0; rg < 2; ++rg)
#pragma unroll
            for (int r = 0; r < 4; ++r) {
                int row = rowBase + rg * 16 + kq * 4 + r;
                mk8[rg * 4 + r] = mask[row];
                ib8[rg * 4 + r] = (row >= (bBlk + 1) * rowsPerBatch) ? 1 : 0;
            }
    }
    float cs1[8], cs2[8], av0[8], av1[8];
#pragma unroll
    for (int ct = 0; ct < 8; ++ct) { cs1[ct] = 0.f; cs2[ct] = 0.f; av0[ct] = 0.f; av1[ct] = 0.f; }
#pragma unroll
    for (int ct = 0; ct < 8; ++ct) {
        int col = ct * 16 + m;
        float bb = bp[col];
#pragma unroll
        for (int rg = 0; rg < 2; ++rg) {
#pragma unroll
            for (int r = 0; r < 4; ++r) {
                int row = rowBase + rg * 16 + kq * 4 + r;
                size_t o = (size_t)row * 128 + col;
                float v = acc[rg][ct][r] + bb;
                if (resid) v += resid[o];
                out[o] = v;
                if (shadow) {
                    int b = row / rowsPerBatch, vert = row - b * rowsPerBatch;
                    shadow[(size_t)(4 * vert + (col >> 5)) * 128 + b * 32 + (col & 31)] =
                        __float2half(v);
                }
                float e = eluf(v);
                cs1[ct] += e; cs2[ct] += e * e;
                if (avgout) {
                    float me = mk8[rg * 4 + r] * e;
                    if (ib8[rg * 4 + r]) av1[ct] += me; else av0[ct] += me;
                }
            }
        }
    }
    if (Sout) {  // fused stats (+ optional avg) for the consuming layer
        __syncthreads();           // all waves done with Bsh/Bsl
        float* red = (float*)Bsh;   // 256 floats: stats
        float* redv = (float*)Bsl;  // 256 floats: avg numerators (2 batch planes)
        red[t] = 0.f;
        if (avgout) redv[t] = 0.f;
        __syncthreads();
#pragma unroll
        for (int ct = 0; ct < 8; ++ct) {
            cs1[ct] += __shfl_xor(cs1[ct], 16); cs1[ct] += __shfl_xor(cs1[ct], 32);
            cs2[ct] += __shfl_xor(cs2[ct], 16); cs2[ct] += __shfl_xor(cs2[ct], 32);
            if (avgout) {
                av0[ct] += __shfl_xor(av0[ct], 16); av0[ct] += __shfl_xor(av0[ct], 32);
                av1[ct] += __shfl_xor(av1[ct], 16); av1[ct] += __shfl_xor(av1[ct], 32);
            }
        }
        if (kq == 0) {
#pragma unroll
            for (int ct = 0; ct < 8; ++ct) {
                atomicAdd(&red[ct * 16 + m], cs1[ct]);
                atomicAdd(&red[128 + ct * 16 + m], cs2[ct]);
                if (avgout) {
                    atomicAdd(&redv[ct * 16 + m], av0[ct]);
                    atomicAdd(&redv[128 + ct * 16 + m], av1[ct]);
                }
            }
        }
        __syncthreads();
        if (t < 128) atomicAdd(&Sout[t], red[t]);
        else atomicAdd(&Sout[256 + (t - 128)], red[t]);
        if (avgout) {
            int plane = t >> 7, col = t & 127;
            int b = bBlk + plane;
            if (b < 4) atomicAdd(&avgout[b * 128 + col], redv[t]);
        }
    }
}

__global__ void finalize_avg(const float* __restrict__ avgacc, const float* __restrict__ masksum,
                             float* __restrict__ avg, float* __restrict__ S, float fN) {
    int c = threadIdx.x;
    float s1 = 0.f, s2 = 0.f;
    for (int b = 0; b < 4; ++b) {
        float a = avgacc[b * 128 + c] / masksum[b];
        avg[b * 128 + c] = a;
        s1 += a; s2 += a * a;
    }
    S[128 + c] = s1 * fN;
    S[256 + 128 + c] = s2 * fN;
}

__global__ void fold_final(const float* __restrict__ S, const float* __restrict__ g2,
                           const float* __restrict__ be2, const float* __restrict__ W2,
                           const float* __restrict__ b2, float* __restrict__ W2p, float invR) {
    __shared__ float red[128];
    int c = threadIdx.x;
    float mean = S[c] * invR;
    float var = S[256 + c] * invR - mean * mean;
    float s = g2[c] / sqrtf(var + EPS);
    float w = W2[c];
    W2p[c] = s * w;
    red[c] = (be2[c] - mean * s) * w;
    __syncthreads();
    for (int st = 64; st > 0; st >>= 1) {
        if (c < st) red[c] += red[c + st];
        __syncthreads();
    }
    if (c == 0) W2p[128] = b2[0] + red[0];
}

__global__ void final_out_kernel(const float* __restrict__ f, const float* __restrict__ W2p,
                                 float* __restrict__ out) {
    int t = threadIdx.x;
    int w = t >> 6, lane = t & 63;
    int row = blockIdx.x * 4 + w;
    float a = eluf(f[(size_t)row * 128 + lane]) * W2p[lane] +
              eluf(f[(size_t)row * 128 + 64 + lane]) * W2p[64 + lane];
    for (int off = 32; off > 0; off >>= 1) a += __shfl_down(a, off);
    if (lane == 0) out[row] = a + W2p[128];
}

extern "C" void kernel_launch(void* const* d_in, const int* in_sizes, int n_in,
                              void* d_out, int out_size, void* d_ws, size_t ws_size,
                              hipStream_t stream) {
    const float* inputs = (const float*)d_in[0];
    const float* mask = (const float*)d_in[1];
    const int* Di_rows = (const int*)d_in[2];
    const int* Di_cols = (const int*)d_in[3];
    const float* Di_vals = (const float*)d_in[4];
    const int* DiA_rows = (const int*)d_in[5];
    const int* DiA_cols = (const int*)d_in[6];
    const float* DiA_vals = (const float*)d_in[7];
    const float* W1 = (const float*)d_in[8];
    const float* b1 = (const float*)d_in[9];
    const float* rn_gamma = (const float*)d_in[10];
    const float* rn_beta = (const float*)d_in[11];
    const float* rn_W = (const float*)d_in[12];
    const float* rn_b = (const float*)d_in[13];
    const float* g2 = (const float*)d_in[14];
    const float* be2 = (const float*)d_in[15];
    const float* W2 = (const float*)d_in[16];
    const float* b2 = (const float*)d_in[17];
    float* out = (float*)d_out;

    const int B = 4;
    const int BN = in_sizes[1];      // 48000
    const int N = BN / B;            // 12000
    const int BF = out_size;         // 96000
    const int Fn = BF / B;           // 24000
    const int nnz = in_sizes[2];     // 1,152,000
    const int RA = 4 * N;            // 48000
    const int RD = 4 * Fn;           // 96000

    float* ws = (float*)d_ws;
    size_t off = 0;
    float* vA = ws + off;  off += (size_t)BN * 128;
    float* fA = ws + off;  off += (size_t)BF * 128;
    float* msg = ws + off; off += (size_t)BF * 128;
    __half* vH = (__half*)(ws + off); off += (size_t)RA * 128 / 2;  // [r4][b][32] fp16
    __half* fH = (__half*)(ws + off); off += (size_t)RD * 128 / 2;
    int* ptrA    = (int*)(ws + off);  off += (size_t)RA + 4;
    int2* edgesA = (int2*)(ws + off); off += (size_t)nnz * 2;
    int* ptrD    = (int*)(ws + off);  off += (size_t)RD + 4;
    int2* edgesD = (int2*)(ws + off); off += (size_t)nnz * 2;
    int* tmpfill = (int*)(ws + off);  off += (size_t)RD;
    int* partials = (int*)(ws + off); off += 256;
    float* Sarena = ws + off; off += 33 * 512;   // pre-zeroed stats slots (2i+j map)
    float* Aarena = ws + off; off += 16 * 512;   // pre-zeroed avg-numerator slots
    float* msum = ws + off;   off += 4;          // masksum (fully written by kernel)
    float* avg = ws + off;    off += 512;
    short* Wh = (short*)(ws + off); off += 128 * 256 / 2;
    short* Wl = (short*)(ws + off); off += 128 * 256 / 2;
    float* bp = ws + off;  off += 128;
    float* W2p = ws + off; off += 132;

    const int eBlocks = nnz / 256;
    const int PA = (RA + 1023) / 1024;
    const int PD = (RD + 1023) / 1024;

    hipMemsetAsync(Sarena, 0, (33 * 512 + 16 * 512) * 4, stream);
    hipMemsetAsync(fA, 0, (size_t)BF * 128 * 4, stream);
    // fH memset no longer needed: layer-0 DiA spmm (its only pre-write reader) is skipped.

    // ---- build CSR for DiA ----
    hipMemsetAsync(tmpfill, 0, (size_t)RA * 4, stream);
    hist_kernel<<<eBlocks, 256, 0, stream>>>(DiA_rows, tmpfill);
    partial_kernel<<<PA, 256, 0, stream>>>(tmpfill, partials, RA);
    scanp_kernel<<<1, 256, 0, stream>>>(partials, ptrA, PA, RA, nnz);
    apply_kernel<<<PA, 256, 0, stream>>>(tmpfill, partials, ptrA, RA);
    scatter_kernel<<<eBlocks, 256, 0, stream>>>(DiA_rows, DiA_cols, DiA_vals, tmpfill, edgesA);
    // ---- build CSR for Di ----
    hipMemsetAsync(tmpfill, 0, (size_t)RD * 4, stream);
    hist_kernel<<<eBlocks, 256, 0, stream>>>(Di_rows, tmpfill);
    partial_kernel<<<PD, 256, 0, stream>>>(tmpfill, partials, RD);
    scanp_kernel<<<1, 256, 0, stream>>>(partials, ptrD, PD, RD, nnz);
    apply_kernel<<<PD, 256, 0, stream>>>(tmpfill, partials, ptrD, RD);
    scatter_kernel<<<eBlocks, 256, 0, stream>>>(Di_rows, Di_cols, Di_vals, tmpfill, edgesD);

    // S slot map: conv layer (i,j) -> Sarena + 512*(2i+j); final conv -> slot 32.
    // Avg-numerator map: avg block at odd i, conv j -> Aarena + 512*(i-1+j).
    auto slot = [&](int i, int j) { return Sarena + 512 * (2 * i + j); };
    float* Sfinal = Sarena + 512 * 32;

    masksum_kernel<<<B, 256, 0, stream>>>(mask, msum, N);
    conv1_kernel<<<BN / 64, 256, 0, stream>>>(inputs, W1, b1, vA, vH, N, slot(0, 0));

    for (int i = 0; i < 15; ++i) {   // layer 15 (avg) is dead: output depends only on f
        if ((i & 1) == 0) {
            const float* g0 = rn_gamma + (size_t)(i * 2 + 0) * 256;
            const float* be0 = rn_beta + (size_t)(i * 2 + 0) * 256;
            const float* Wl0 = rn_W + (size_t)(i * 2 + 0) * 256 * 128;
            const float* bl0 = rn_b + (size_t)(i * 2 + 0) * 128;
            const float* g1 = rn_gamma + (size_t)(i * 2 + 1) * 256;
            const float* be1 = rn_beta + (size_t)(i * 2 + 1) * 256;
            const float* Wl1 = rn_W + (size_t)(i * 2 + 1) * 256 * 128;
            const float* bl1 = rn_b + (size_t)(i * 2 + 1) * 128;
            // v-gemm feeds avg block i+1 (if any): stats + avg numerators
            float* SoutV = (i < 14) ? slot(i + 1, 0) : nullptr;
            float* avgV = (i < 14) ? (Aarena + 512 * i) : nullptr;

            if (i == 0) {
                // f == 0 -> msg_v == 0 exactly: skip spmm; slot(0,0) B-half stays 0.
                fold_kernel<<<128, 256, 0, stream>>>(slot(0, 0), g0, be0, Wl0, bl0,
                                                     Wh, Wl, bp, 1.f / BN);
                gemm_mfma<<<BN / 128, 256, 0, stream>>>(vA, nullptr, Wh, Wl, bp, vA, vA,
                                                        vH, SoutV, mask, avgV, N, 2, 1);
            } else {
                spmm_csr_kernel<<<RA / 32, 1024, 0, stream>>>(ptrA, edgesA,
                                                              (const __half2*)fH, msg, RA,
                                                              slot(i, 0));
                fold_kernel<<<128, 256, 0, stream>>>(slot(i, 0), g0, be0, Wl0, bl0,
                                                     Wh, Wl, bp, 1.f / BN);
                gemm_mfma<<<BN / 128, 256, 0, stream>>>(vA, msg, Wh, Wl, bp, vA, vA,
                                                        vH, SoutV, mask, avgV, N, 0, 1);
            }

            // msg_f = Di @ v_out (gather vH); B-half stats -> slot(i,1)
            spmm_csr_kernel<<<RD / 32, 1024, 0, stream>>>(ptrD, edgesD, (const __half2*)vH,
                                                          msg, RD, slot(i, 1));
            fold_kernel<<<128, 256, 0, stream>>>(slot(i, 1), g1, be1, Wl1, bl1, Wh, Wl,
                                                 bp, 1.f / BF);
            gemm_mfma<<<BF / 128, 256, 0, stream>>>(fA, msg, Wh, Wl, bp, nullptr, fA, fH,
                                                    (i < 14) ? slot(i + 2, 1) : Sfinal,
                                                    nullptr, nullptr, Fn, 0, 1);
        } else {
            for (int j = 0; j < 2; ++j) {
                const float* g = rn_gamma + (size_t)(i * 2 + j) * 256;
                const float* be = rn_beta + (size_t)(i * 2 + j) * 256;
                const float* Wlw = rn_W + (size_t)(i * 2 + j) * 256 * 128;
                const float* bl = rn_b + (size_t)(i * 2 + j) * 128;
                const float* src = (j == 0) ? vA : msg;
                float* dst = (j == 0) ? msg : vA;
                const float* resid = (j == 0) ? nullptr : vA;
                __half* shadow = (j == 0) ? nullptr : vH;
                // j=0 stats consumer: this layer's j=1; j=1 consumer: dir(i+1) slot0
                float* Sout = (j == 0) ? slot(i, 1) : slot(i + 1, 0);
                // j=0 gemm also produces j=1's avg numerators
                float* avgO = (j == 0) ? (Aarena + 512 * i) : nullptr;

                float* avgacc = Aarena + 512 * (i - 1 + j);
                finalize_avg<<<1, 128, 0, stream>>>(avgacc, msum, avg, slot(i, j),
                                                    (float)N);
                fold_kernel<<<128, 256, 0, stream>>>(slot(i, j), g, be, Wlw, bl, Wh, Wl,
                                                     bp, 1.f / BN);
                gemm_mfma<<<BN / 128, 256, 0, stream>>>(src, avg, Wh, Wl, bp, resid, dst,
                                                        shadow, Sout, mask, avgO, N, 1, 0);
            }
        }
    }

    fold_final<<<1, 128, 0, stream>>>(Sfinal, g2, be2, W2, b2, W2p, 1.f / BF);
    final_out_kernel<<<BF / 4, 256, 0, stream>>>(fA, W2p, out);
}